// Round 1
// baseline (704.711 us; speedup 1.0000x reference)
//
#include <hip/hip_runtime.h>

#define B_ 8
#define N_ 8192
#define S_ 2048
#define D1_ 128
#define D2_ 256
#define C0_ 384
#define C1_ 256
#define C2_ 128
#define BN_EPS 1e-5f

// ---------------------------------------------------------------------------
// insert (d,i) into sorted-ascending top-3 (tie-break: smaller index wins)
// ---------------------------------------------------------------------------
__device__ __forceinline__ void insert3(float d, int i,
    float& d0, int& i0, float& d1, int& i1, float& d2, int& i2) {
  if (d < d2 || (d == d2 && i < i2)) {
    if (d < d1 || (d == d1 && i < i1)) {
      d2 = d1; i2 = i1;
      if (d < d0 || (d == d0 && i < i0)) { d1 = d0; i1 = i0; d0 = d; i0 = i; }
      else { d1 = d; i1 = i; }
    } else { d2 = d; i2 = i; }
  }
}

// ---------------------------------------------------------------------------
// K1: 3-NN + inverse-distance-weighted interpolation.
// Block = 256 threads = 64 queries x 4 threads. Grid = (N/64, B).
// Writes interp [B, D2, N] (channel-major, f32).
// ---------------------------------------------------------------------------
__global__ __launch_bounds__(256) void knn_interp_kernel(
    const float* __restrict__ xyz_sa, const float* __restrict__ xyz_now,
    const float* __restrict__ points_now, float* __restrict__ interp)
{
  __shared__ float4 sp[S_];          // (px,py,pz,|p|^2) per candidate
  __shared__ int   s_idx[64][3];
  __shared__ float s_w[64][3];

  const int b  = blockIdx.y;
  const int n0 = blockIdx.x * 64;

  // stage candidates (with precomputed squared norm)
  const float* xb = xyz_now + (size_t)b * 3 * S_;
  for (int i = threadIdx.x; i < S_; i += 256) {
    float px = xb[i], py = xb[S_ + i], pz = xb[2 * S_ + i];
    sp[i] = make_float4(px, py, pz, px * px + py * py + pz * pz);
  }
  __syncthreads();

  const int q = threadIdx.x >> 2;    // query within block (0..63)
  const int t = threadIdx.x & 3;     // sub-scanner (0..3)
  const int n = n0 + q;

  const float* xq = xyz_sa + (size_t)b * 3 * N_;
  const float qx = xq[n], qy = xq[N_ + n], qz = xq[2 * N_ + n];
  const float qq = qx * qx + qy * qy + qz * qz;

  float d0 = 3.4e38f, d1 = 3.4e38f, d2 = 3.4e38f;
  int   i0 = 0x7fffffff, i1 = 0x7fffffff, i2 = 0x7fffffff;

  for (int it = 0; it < S_ / 4; ++it) {
    int s = (it << 2) | t;           // lanes of a quad read 4 consecutive pts
    float4 p = sp[s];
    float dot = qx * p.x + qy * p.y + qz * p.z;
    float d = qq - 2.0f * dot + p.w; // same expansion as reference
    insert3(d, s, d0, i0, d1, i1, d2, i2);
  }

  // merge the 4 scanners' top-3 via shuffle (symmetric butterfly)
  #pragma unroll
  for (int m = 1; m <= 2; m <<= 1) {
    float od0 = __shfl_xor(d0, m), od1 = __shfl_xor(d1, m), od2 = __shfl_xor(d2, m);
    int   oi0 = __shfl_xor(i0, m), oi1 = __shfl_xor(i1, m), oi2 = __shfl_xor(i2, m);
    insert3(od0, oi0, d0, i0, d1, i1, d2, i2);
    insert3(od1, oi1, d0, i0, d1, i1, d2, i2);
    insert3(od2, oi2, d0, i0, d1, i1, d2, i2);
  }

  if (t == 0) {
    float r0 = 1.0f / (d0 + 1e-8f);
    float r1 = 1.0f / (d1 + 1e-8f);
    float r2 = 1.0f / (d2 + 1e-8f);
    float rs = 1.0f / (r0 + r1 + r2);
    s_idx[q][0] = i0; s_idx[q][1] = i1; s_idx[q][2] = i2;
    s_w[q][0] = r0 * rs; s_w[q][1] = r1 * rs; s_w[q][2] = r2 * rs;
  }
  __syncthreads();

  // gather + weighted sum; remap threads for coalesced writes:
  // wave = one d, 64 consecutive n.
  const int n_off = threadIdx.x & 63;
  const int d_off = threadIdx.x >> 6; // 0..3
  const int j0 = s_idx[n_off][0], j1 = s_idx[n_off][1], j2 = s_idx[n_off][2];
  const float w0 = s_w[n_off][0], w1 = s_w[n_off][1], w2 = s_w[n_off][2];
  const float* pnb = points_now + (size_t)b * D2_ * S_;
  float* outb = interp + (size_t)b * D2_ * N_ + n0;
  for (int d = d_off; d < D2_; d += 4) {
    const float* row = pnb + (size_t)d * S_;
    float v = w0 * row[j0] + w1 * row[j1] + w2 * row[j2];
    outb[(size_t)d * N_ + n_off] = v;
  }
}

// ---------------------------------------------------------------------------
// K2: GEMM1  y0[b,o,n] = W0[o,:] . x[b,:,n] + b0[o],  x = concat(points_sa, interp)
// Tiles 128x128, BK=32, block 256 threads, 8x8 accum per thread.
// Fused per-channel sum/sumsq via shuffle-reduce + atomicAdd.
// ---------------------------------------------------------------------------
__global__ __launch_bounds__(256) void gemm1_kernel(
    const float* __restrict__ points_sa, const float* __restrict__ interp,
    const float* __restrict__ W0, const float* __restrict__ b0,
    float* __restrict__ y0, float* __restrict__ stats)
{
  __shared__ float As[32][132];   // [k][o], padded
  __shared__ float Bs[32][128];   // [k][n]

  const int b  = blockIdx.z;
  const int n0 = blockIdx.x * 128;
  const int o0 = blockIdx.y * 128;
  const int tid = threadIdx.x;
  const int tx = tid & 15, ty = tid >> 4;

  float acc[8][8];
  #pragma unroll
  for (int i = 0; i < 8; ++i)
    #pragma unroll
    for (int j = 0; j < 8; ++j) acc[i][j] = 0.0f;

  for (int kt = 0; kt < C0_; kt += 32) {
    // A tile: W0 rows o0..o0+127, cols kt..kt+31, transposed into As[k][o]
    {
      const int row8 = tid >> 3;
      const int c4 = (tid & 7) << 2;
      #pragma unroll
      for (int r = 0; r < 4; ++r) {
        int o = r * 32 + row8;
        float4 v = *(const float4*)(W0 + (size_t)(o0 + o) * C0_ + kt + c4);
        As[c4 + 0][o] = v.x; As[c4 + 1][o] = v.y;
        As[c4 + 2][o] = v.z; As[c4 + 3][o] = v.w;
      }
    }
    // B tile: x rows kt..kt+31 (from points_sa or interp), cols n0..n0+127
    {
      const float* src = (kt < D1_)
          ? points_sa + ((size_t)b * D1_ + kt) * N_ + n0
          : interp    + ((size_t)b * D2_ + (kt - D1_)) * N_ + n0;
      const int rr = tid >> 5;
      const int c4 = (tid & 31) << 2;
      #pragma unroll
      for (int r = 0; r < 4; ++r) {
        int c = r * 8 + rr;
        *(float4*)&Bs[c][c4] = *(const float4*)(src + (size_t)c * N_ + c4);
      }
    }
    __syncthreads();
    #pragma unroll 4
    for (int k = 0; k < 32; ++k) {
      float a[8], bb[8];
      *(float4*)&a[0]  = *(const float4*)&As[k][ty * 8];
      *(float4*)&a[4]  = *(const float4*)&As[k][ty * 8 + 4];
      *(float4*)&bb[0] = *(const float4*)&Bs[k][tx * 8];
      *(float4*)&bb[4] = *(const float4*)&Bs[k][tx * 8 + 4];
      #pragma unroll
      for (int i = 0; i < 8; ++i)
        #pragma unroll
        for (int j = 0; j < 8; ++j)
          acc[i][j] = fmaf(a[i], bb[j], acc[i][j]);
    }
    __syncthreads();
  }

  float* outb = y0 + ((size_t)b * C1_ + o0) * N_ + n0;
  #pragma unroll
  for (int i = 0; i < 8; ++i) {
    const int o = ty * 8 + i;
    const float bias = b0[o0 + o];
    float s1 = 0.0f, s2 = 0.0f;
    float v[8];
    #pragma unroll
    for (int j = 0; j < 8; ++j) {
      float y = acc[i][j] + bias;
      v[j] = y; s1 += y; s2 += y * y;
    }
    *(float4*)(outb + (size_t)o * N_ + tx * 8)     = make_float4(v[0], v[1], v[2], v[3]);
    *(float4*)(outb + (size_t)o * N_ + tx * 8 + 4) = make_float4(v[4], v[5], v[6], v[7]);
    #pragma unroll
    for (int m = 1; m < 16; m <<= 1) { s1 += __shfl_xor(s1, m); s2 += __shfl_xor(s2, m); }
    if (tx == 0) {
      atomicAdd(&stats[o0 + o], s1);
      atomicAdd(&stats[C1_ + o0 + o], s2);
    }
  }
}

// ---------------------------------------------------------------------------
// K4: GEMM2  y1[b,p,n] = W1[p,:] . relu(bn0(y0[b,:,n])) + b1[p]
// BN0 applied on-the-fly during B-tile load via precomputed (a,c).
// ---------------------------------------------------------------------------
__global__ __launch_bounds__(256) void gemm2_kernel(
    const float* __restrict__ y0, const float* __restrict__ coef,
    const float* __restrict__ W1, const float* __restrict__ b1,
    float* __restrict__ y1, float* __restrict__ stats)
{
  __shared__ float As[32][132];
  __shared__ float Bs[32][128];

  const int b  = blockIdx.z;
  const int n0 = blockIdx.x * 128;
  const int tid = threadIdx.x;
  const int tx = tid & 15, ty = tid >> 4;

  float acc[8][8];
  #pragma unroll
  for (int i = 0; i < 8; ++i)
    #pragma unroll
    for (int j = 0; j < 8; ++j) acc[i][j] = 0.0f;

  for (int kt = 0; kt < C1_; kt += 32) {
    {
      const int row8 = tid >> 3;
      const int c4 = (tid & 7) << 2;
      #pragma unroll
      for (int r = 0; r < 4; ++r) {
        int o = r * 32 + row8;
        float4 v = *(const float4*)(W1 + (size_t)o * C1_ + kt + c4);
        As[c4 + 0][o] = v.x; As[c4 + 1][o] = v.y;
        As[c4 + 2][o] = v.z; As[c4 + 3][o] = v.w;
      }
    }
    {
      const int rr = tid >> 5;
      const int c4 = (tid & 31) << 2;
      #pragma unroll
      for (int r = 0; r < 4; ++r) {
        int c = r * 8 + rr;
        int cg = kt + c;
        float aa = coef[cg], cc = coef[C1_ + cg];
        const float* src = y0 + ((size_t)b * C1_ + cg) * N_ + n0;
        float4 v = *(const float4*)(src + c4);
        v.x = fmaxf(0.0f, fmaf(v.x, aa, cc));
        v.y = fmaxf(0.0f, fmaf(v.y, aa, cc));
        v.z = fmaxf(0.0f, fmaf(v.z, aa, cc));
        v.w = fmaxf(0.0f, fmaf(v.w, aa, cc));
        *(float4*)&Bs[c][c4] = v;
      }
    }
    __syncthreads();
    #pragma unroll 4
    for (int k = 0; k < 32; ++k) {
      float a[8], bb[8];
      *(float4*)&a[0]  = *(const float4*)&As[k][ty * 8];
      *(float4*)&a[4]  = *(const float4*)&As[k][ty * 8 + 4];
      *(float4*)&bb[0] = *(const float4*)&Bs[k][tx * 8];
      *(float4*)&bb[4] = *(const float4*)&Bs[k][tx * 8 + 4];
      #pragma unroll
      for (int i = 0; i < 8; ++i)
        #pragma unroll
        for (int j = 0; j < 8; ++j)
          acc[i][j] = fmaf(a[i], bb[j], acc[i][j]);
    }
    __syncthreads();
  }

  float* outb = y1 + ((size_t)b * C2_) * N_ + n0;
  #pragma unroll
  for (int i = 0; i < 8; ++i) {
    const int o = ty * 8 + i;
    const float bias = b1[o];
    float s1 = 0.0f, s2 = 0.0f;
    float v[8];
    #pragma unroll
    for (int j = 0; j < 8; ++j) {
      float y = acc[i][j] + bias;
      v[j] = y; s1 += y; s2 += y * y;
    }
    *(float4*)(outb + (size_t)o * N_ + tx * 8)     = make_float4(v[0], v[1], v[2], v[3]);
    *(float4*)(outb + (size_t)o * N_ + tx * 8 + 4) = make_float4(v[4], v[5], v[6], v[7]);
    #pragma unroll
    for (int m = 1; m < 16; m <<= 1) { s1 += __shfl_xor(s1, m); s2 += __shfl_xor(s2, m); }
    if (tx == 0) {
      atomicAdd(&stats[o], s1);
      atomicAdd(&stats[C2_ + o], s2);
    }
  }
}

// ---------------------------------------------------------------------------
// BN coefficient kernels: a = g*rsqrt(var+eps), c = be - mean*a
// ---------------------------------------------------------------------------
__global__ void bn_coef_kernel(const float* __restrict__ g, const float* __restrict__ be,
                               const float* __restrict__ stats, float* __restrict__ coef,
                               int C)
{
  int o = threadIdx.x;
  if (o < C) {
    const float invM = 1.0f / 65536.0f;   // B*N
    float mean = stats[o] * invM;
    float var  = stats[C + o] * invM - mean * mean;
    float a = g[o] / sqrtf(var + BN_EPS);
    float c = be[o] - mean * a;
    coef[o] = a;
    coef[C + o] = c;
  }
}

__global__ void zero_kernel(float* __restrict__ p, int n)
{
  int i = blockIdx.x * blockDim.x + threadIdx.x;
  if (i < n) p[i] = 0.0f;
}

// ---------------------------------------------------------------------------
// K6: final BN1 + ReLU elementwise
// ---------------------------------------------------------------------------
__global__ __launch_bounds__(256) void final_kernel(
    const float* __restrict__ y1, const float* __restrict__ cf, float* __restrict__ out)
{
  const size_t total4 = (size_t)B_ * C2_ * N_ / 4;
  const size_t stride = (size_t)gridDim.x * blockDim.x;
  for (size_t f = (size_t)blockIdx.x * blockDim.x + threadIdx.x; f < total4; f += stride) {
    size_t base = f * 4;
    int p = (int)((base >> 13) & (C2_ - 1));   // 8192 floats per channel-row
    float a = cf[p], c = cf[C2_ + p];
    float4 v = *(const float4*)(y1 + base);
    float4 r;
    r.x = fmaxf(0.0f, fmaf(v.x, a, c));
    r.y = fmaxf(0.0f, fmaf(v.y, a, c));
    r.z = fmaxf(0.0f, fmaf(v.z, a, c));
    r.w = fmaxf(0.0f, fmaf(v.w, a, c));
    *(float4*)(out + base) = r;
  }
}

// ---------------------------------------------------------------------------
extern "C" void kernel_launch(void* const* d_in, const int* in_sizes, int n_in,
                              void* d_out, int out_size, void* d_ws, size_t ws_size,
                              hipStream_t stream)
{
  const float* xyz_sa     = (const float*)d_in[0];
  const float* xyz_now    = (const float*)d_in[1];
  const float* points_sa  = (const float*)d_in[2];
  const float* points_now = (const float*)d_in[3];
  const float* W0  = (const float*)d_in[4];
  const float* b0  = (const float*)d_in[5];
  const float* g0  = (const float*)d_in[6];
  const float* be0 = (const float*)d_in[7];
  const float* W1  = (const float*)d_in[8];
  const float* b1  = (const float*)d_in[9];
  const float* g1  = (const float*)d_in[10];
  const float* be1 = (const float*)d_in[11];
  // d_in[12] = k (always 3)

  float* ws     = (float*)d_ws;
  float* interp = ws;                        // [B, D2, N]  = 16,777,216 f
  float* y0     = ws + (size_t)16777216;     // [B, C1, N]  = 16,777,216 f
  float* y1     = ws;                        // reuse interp region [B, C2, N]
  float* stats  = ws + (size_t)2 * 16777216; // 768 f: L0 sum/sumsq (512), L1 (256)
  float* coef   = stats + 768;               // 768 f: a0,c0 (512); a1,c1 (256)
  float* out    = (float*)d_out;

  hipLaunchKernelGGL(zero_kernel, dim3(1), dim3(768), 0, stream, stats, 768);
  hipLaunchKernelGGL(knn_interp_kernel, dim3(N_ / 64, B_), dim3(256), 0, stream,
                     xyz_sa, xyz_now, points_now, interp);
  hipLaunchKernelGGL(gemm1_kernel, dim3(N_ / 128, C1_ / 128, B_), dim3(256), 0, stream,
                     points_sa, interp, W0, b0, y0, stats);
  hipLaunchKernelGGL(bn_coef_kernel, dim3(1), dim3(256), 0, stream,
                     g0, be0, stats, coef, C1_);
  hipLaunchKernelGGL(gemm2_kernel, dim3(N_ / 128, 1, B_), dim3(256), 0, stream,
                     y0, coef, W1, b1, y1, stats + 512);
  hipLaunchKernelGGL(bn_coef_kernel, dim3(1), dim3(128), 0, stream,
                     g1, be1, stats + 512, coef + 512, C2_);
  hipLaunchKernelGGL(final_kernel, dim3(2048), dim3(256), 0, stream,
                     y1, coef + 512, out);
}

// Round 2
// 649.029 us; speedup vs baseline: 1.0858x; 1.0858x over previous
//
#include <hip/hip_runtime.h>

#define B_ 8
#define N_ 8192
#define S_ 2048
#define D1_ 128
#define D2_ 256
#define C0_ 384
#define C1_ 256
#define C2_ 128
#define BN_EPS 1e-5f

// ---------------------------------------------------------------------------
// insert (d,i) into sorted-ascending top-3 (tie-break: smaller index wins)
// ---------------------------------------------------------------------------
__device__ __forceinline__ void insert3(float d, int i,
    float& d0, int& i0, float& d1, int& i1, float& d2, int& i2) {
  if (d < d2 || (d == d2 && i < i2)) {
    if (d < d1 || (d == d1 && i < i1)) {
      d2 = d1; i2 = i1;
      if (d < d0 || (d == d0 && i < i0)) { d1 = d0; i1 = i0; d0 = d; i0 = i; }
      else { d1 = d; i1 = i; }
    } else { d2 = d; i2 = i; }
  }
}

// ---------------------------------------------------------------------------
// K0: transpose points_now [B][D2][S] -> pnT [B][S][D2]
// ---------------------------------------------------------------------------
__global__ __launch_bounds__(256) void transpose_kernel(
    const float* __restrict__ in, float* __restrict__ out)
{
  __shared__ float tile[32][33];
  const int b  = blockIdx.z;
  const int s0 = blockIdx.x * 32;
  const int d0 = blockIdx.y * 32;
  const int tx = threadIdx.x & 31, ty = threadIdx.x >> 5;

  const float* inb = in + ((size_t)b * D2_ + d0) * S_ + s0;
  #pragma unroll
  for (int r = 0; r < 4; ++r) {
    int d = r * 8 + ty;
    tile[d][tx] = inb[(size_t)d * S_ + tx];
  }
  __syncthreads();
  float* outb = out + ((size_t)b * S_ + s0) * D2_ + d0;
  #pragma unroll
  for (int r = 0; r < 4; ++r) {
    int s = r * 8 + ty;
    outb[(size_t)s * D2_ + tx] = tile[tx][s];
  }
}

// ---------------------------------------------------------------------------
// K1: 3-NN + inverse-distance-weighted interpolation (fused, coalesced).
// Block = 256 threads = 64 queries. Phase 1: 4 threads/query top-3 select.
// Phase 2: one WAVE per query; 64 lanes x float4 = 256 channels, coalesced
// reads from pnT [B][S][D2] and coalesced writes to interpT [B][N][D2].
// ---------------------------------------------------------------------------
__global__ __launch_bounds__(256) void knn_interp_kernel(
    const float* __restrict__ xyz_sa, const float* __restrict__ xyz_now,
    const float* __restrict__ pnT, float* __restrict__ interpT)
{
  __shared__ float4 sp[S_];          // (px,py,pz,|p|^2) per candidate
  __shared__ int   s_idx[64][3];
  __shared__ float s_w[64][3];

  const int b  = blockIdx.y;
  const int n0 = blockIdx.x * 64;

  // stage candidates (with precomputed squared norm)
  const float* xb = xyz_now + (size_t)b * 3 * S_;
  for (int i = threadIdx.x; i < S_; i += 256) {
    float px = xb[i], py = xb[S_ + i], pz = xb[2 * S_ + i];
    sp[i] = make_float4(px, py, pz, px * px + py * py + pz * pz);
  }
  __syncthreads();

  const int q = threadIdx.x >> 2;    // query within block (0..63)
  const int t = threadIdx.x & 3;     // sub-scanner (0..3)
  const int n = n0 + q;

  const float* xq = xyz_sa + (size_t)b * 3 * N_;
  const float qx = xq[n], qy = xq[N_ + n], qz = xq[2 * N_ + n];
  const float qq = qx * qx + qy * qy + qz * qz;

  float d0 = 3.4e38f, d1 = 3.4e38f, d2 = 3.4e38f;
  int   i0 = 0x7fffffff, i1 = 0x7fffffff, i2 = 0x7fffffff;

  for (int it = 0; it < S_ / 4; ++it) {
    int s = (it << 2) | t;           // lanes of a quad read 4 consecutive pts
    float4 p = sp[s];
    float dot = qx * p.x + qy * p.y + qz * p.z;
    float d = qq - 2.0f * dot + p.w; // same expansion as reference
    insert3(d, s, d0, i0, d1, i1, d2, i2);
  }

  // merge the 4 scanners' top-3 via shuffle (symmetric butterfly)
  #pragma unroll
  for (int m = 1; m <= 2; m <<= 1) {
    float od0 = __shfl_xor(d0, m), od1 = __shfl_xor(d1, m), od2 = __shfl_xor(d2, m);
    int   oi0 = __shfl_xor(i0, m), oi1 = __shfl_xor(i1, m), oi2 = __shfl_xor(i2, m);
    insert3(od0, oi0, d0, i0, d1, i1, d2, i2);
    insert3(od1, oi1, d0, i0, d1, i1, d2, i2);
    insert3(od2, oi2, d0, i0, d1, i1, d2, i2);
  }

  if (t == 0) {
    float r0 = 1.0f / (d0 + 1e-8f);
    float r1 = 1.0f / (d1 + 1e-8f);
    float r2 = 1.0f / (d2 + 1e-8f);
    float rs = 1.0f / (r0 + r1 + r2);
    s_idx[q][0] = i0; s_idx[q][1] = i1; s_idx[q][2] = i2;
    s_w[q][0] = r0 * rs; s_w[q][1] = r1 * rs; s_w[q][2] = r2 * rs;
  }
  __syncthreads();

  // Phase 2: wave-per-query gather, fully coalesced.
  const int wave = threadIdx.x >> 6;  // 0..3
  const int lane = threadIdx.x & 63;
  const float* pb = pnT + (size_t)b * S_ * D2_;
  float* ob = interpT + ((size_t)b * N_ + n0) * D2_;
  #pragma unroll 2
  for (int i = 0; i < 16; ++i) {
    const int qi = wave * 16 + i;
    const int j0 = s_idx[qi][0], j1 = s_idx[qi][1], j2 = s_idx[qi][2];
    const float w0 = s_w[qi][0], w1 = s_w[qi][1], w2 = s_w[qi][2];
    float4 f0 = *(const float4*)(pb + (size_t)j0 * D2_ + lane * 4);
    float4 f1 = *(const float4*)(pb + (size_t)j1 * D2_ + lane * 4);
    float4 f2 = *(const float4*)(pb + (size_t)j2 * D2_ + lane * 4);
    float4 r;
    r.x = w0 * f0.x + w1 * f1.x + w2 * f2.x;
    r.y = w0 * f0.y + w1 * f1.y + w2 * f2.y;
    r.z = w0 * f0.z + w1 * f1.z + w2 * f2.z;
    r.w = w0 * f0.w + w1 * f1.w + w2 * f2.w;
    *(float4*)(ob + (size_t)qi * D2_ + lane * 4) = r;
  }
}

// ---------------------------------------------------------------------------
// K2: GEMM1  y0[b,o,n] = W0[o,:] . x[b,:,n] + b0[o]
// x = concat(points_sa [D1][N], interpT [N][D2] transposed on load)
// Tiles 128x128, BK=32, block 256 threads, 8x8 accum per thread.
// Fused per-channel sum/sumsq via shuffle-reduce + atomicAdd.
// ---------------------------------------------------------------------------
__global__ __launch_bounds__(256) void gemm1_kernel(
    const float* __restrict__ points_sa, const float* __restrict__ interpT,
    const float* __restrict__ W0, const float* __restrict__ b0,
    float* __restrict__ y0, float* __restrict__ stats)
{
  __shared__ float As[32][132];   // [k][o], padded
  __shared__ float Bs[32][132];   // [k][n], padded (transposed writes hit it)

  const int b  = blockIdx.z;
  const int n0 = blockIdx.x * 128;
  const int o0 = blockIdx.y * 128;
  const int tid = threadIdx.x;
  const int tx = tid & 15, ty = tid >> 4;

  float acc[8][8];
  #pragma unroll
  for (int i = 0; i < 8; ++i)
    #pragma unroll
    for (int j = 0; j < 8; ++j) acc[i][j] = 0.0f;

  for (int kt = 0; kt < C0_; kt += 32) {
    // A tile: W0 rows o0..o0+127, cols kt..kt+31, transposed into As[k][o]
    {
      const int row8 = tid >> 3;
      const int c4 = (tid & 7) << 2;
      #pragma unroll
      for (int r = 0; r < 4; ++r) {
        int o = r * 32 + row8;
        float4 v = *(const float4*)(W0 + (size_t)(o0 + o) * C0_ + kt + c4);
        As[c4 + 0][o] = v.x; As[c4 + 1][o] = v.y;
        As[c4 + 2][o] = v.z; As[c4 + 3][o] = v.w;
      }
    }
    // B tile: x rows kt..kt+31, cols n0..n0+127
    if (kt < D1_) {
      const float* src = points_sa + ((size_t)b * D1_ + kt) * N_ + n0;
      const int rr = tid >> 5;
      const int c4 = (tid & 31) << 2;
      #pragma unroll
      for (int r = 0; r < 4; ++r) {
        int c = r * 8 + rr;
        *(float4*)&Bs[c][c4] = *(const float4*)(src + (size_t)c * N_ + c4);
      }
    } else {
      // interpT [N][D2]: row n gives 32 consecutive floats of the k-range
      const float* srcT = interpT + ((size_t)b * N_ + n0) * D2_ + (kt - D1_);
      const int cc = (tid & 7) << 2;     // k-chunk 0..28
      const int nb = tid >> 3;           // 0..31
      #pragma unroll
      for (int r = 0; r < 4; ++r) {
        int nl = r * 32 + nb;
        float4 v = *(const float4*)(srcT + (size_t)nl * D2_ + cc);
        Bs[cc + 0][nl] = v.x; Bs[cc + 1][nl] = v.y;
        Bs[cc + 2][nl] = v.z; Bs[cc + 3][nl] = v.w;
      }
    }
    __syncthreads();
    #pragma unroll 4
    for (int k = 0; k < 32; ++k) {
      float a[8], bb[8];
      *(float4*)&a[0]  = *(const float4*)&As[k][ty * 8];
      *(float4*)&a[4]  = *(const float4*)&As[k][ty * 8 + 4];
      *(float4*)&bb[0] = *(const float4*)&Bs[k][tx * 8];
      *(float4*)&bb[4] = *(const float4*)&Bs[k][tx * 8 + 4];
      #pragma unroll
      for (int i = 0; i < 8; ++i)
        #pragma unroll
        for (int j = 0; j < 8; ++j)
          acc[i][j] = fmaf(a[i], bb[j], acc[i][j]);
    }
    __syncthreads();
  }

  float* outb = y0 + ((size_t)b * C1_ + o0) * N_ + n0;
  #pragma unroll
  for (int i = 0; i < 8; ++i) {
    const int o = ty * 8 + i;
    const float bias = b0[o0 + o];
    float s1 = 0.0f, s2 = 0.0f;
    float v[8];
    #pragma unroll
    for (int j = 0; j < 8; ++j) {
      float y = acc[i][j] + bias;
      v[j] = y; s1 += y; s2 += y * y;
    }
    *(float4*)(outb + (size_t)o * N_ + tx * 8)     = make_float4(v[0], v[1], v[2], v[3]);
    *(float4*)(outb + (size_t)o * N_ + tx * 8 + 4) = make_float4(v[4], v[5], v[6], v[7]);
    #pragma unroll
    for (int m = 1; m < 16; m <<= 1) { s1 += __shfl_xor(s1, m); s2 += __shfl_xor(s2, m); }
    if (tx == 0) {
      atomicAdd(&stats[o0 + o], s1);
      atomicAdd(&stats[C1_ + o0 + o], s2);
    }
  }
}

// ---------------------------------------------------------------------------
// K4: GEMM2  y1[b,p,n] = W1[p,:] . relu(bn0(y0[b,:,n])) + b1[p]
// ---------------------------------------------------------------------------
__global__ __launch_bounds__(256) void gemm2_kernel(
    const float* __restrict__ y0, const float* __restrict__ coef,
    const float* __restrict__ W1, const float* __restrict__ b1,
    float* __restrict__ y1, float* __restrict__ stats)
{
  __shared__ float As[32][132];
  __shared__ float Bs[32][128];

  const int b  = blockIdx.z;
  const int n0 = blockIdx.x * 128;
  const int tid = threadIdx.x;
  const int tx = tid & 15, ty = tid >> 4;

  float acc[8][8];
  #pragma unroll
  for (int i = 0; i < 8; ++i)
    #pragma unroll
    for (int j = 0; j < 8; ++j) acc[i][j] = 0.0f;

  for (int kt = 0; kt < C1_; kt += 32) {
    {
      const int row8 = tid >> 3;
      const int c4 = (tid & 7) << 2;
      #pragma unroll
      for (int r = 0; r < 4; ++r) {
        int o = r * 32 + row8;
        float4 v = *(const float4*)(W1 + (size_t)o * C1_ + kt + c4);
        As[c4 + 0][o] = v.x; As[c4 + 1][o] = v.y;
        As[c4 + 2][o] = v.z; As[c4 + 3][o] = v.w;
      }
    }
    {
      const int rr = tid >> 5;
      const int c4 = (tid & 31) << 2;
      #pragma unroll
      for (int r = 0; r < 4; ++r) {
        int c = r * 8 + rr;
        int cg = kt + c;
        float aa = coef[cg], cc = coef[C1_ + cg];
        const float* src = y0 + ((size_t)b * C1_ + cg) * N_ + n0;
        float4 v = *(const float4*)(src + c4);
        v.x = fmaxf(0.0f, fmaf(v.x, aa, cc));
        v.y = fmaxf(0.0f, fmaf(v.y, aa, cc));
        v.z = fmaxf(0.0f, fmaf(v.z, aa, cc));
        v.w = fmaxf(0.0f, fmaf(v.w, aa, cc));
        *(float4*)&Bs[c][c4] = v;
      }
    }
    __syncthreads();
    #pragma unroll 4
    for (int k = 0; k < 32; ++k) {
      float a[8], bb[8];
      *(float4*)&a[0]  = *(const float4*)&As[k][ty * 8];
      *(float4*)&a[4]  = *(const float4*)&As[k][ty * 8 + 4];
      *(float4*)&bb[0] = *(const float4*)&Bs[k][tx * 8];
      *(float4*)&bb[4] = *(const float4*)&Bs[k][tx * 8 + 4];
      #pragma unroll
      for (int i = 0; i < 8; ++i)
        #pragma unroll
        for (int j = 0; j < 8; ++j)
          acc[i][j] = fmaf(a[i], bb[j], acc[i][j]);
    }
    __syncthreads();
  }

  float* outb = y1 + ((size_t)b * C2_) * N_ + n0;
  #pragma unroll
  for (int i = 0; i < 8; ++i) {
    const int o = ty * 8 + i;
    const float bias = b1[o];
    float s1 = 0.0f, s2 = 0.0f;
    float v[8];
    #pragma unroll
    for (int j = 0; j < 8; ++j) {
      float y = acc[i][j] + bias;
      v[j] = y; s1 += y; s2 += y * y;
    }
    *(float4*)(outb + (size_t)o * N_ + tx * 8)     = make_float4(v[0], v[1], v[2], v[3]);
    *(float4*)(outb + (size_t)o * N_ + tx * 8 + 4) = make_float4(v[4], v[5], v[6], v[7]);
    #pragma unroll
    for (int m = 1; m < 16; m <<= 1) { s1 += __shfl_xor(s1, m); s2 += __shfl_xor(s2, m); }
    if (tx == 0) {
      atomicAdd(&stats[o], s1);
      atomicAdd(&stats[C2_ + o], s2);
    }
  }
}

// ---------------------------------------------------------------------------
__global__ void bn_coef_kernel(const float* __restrict__ g, const float* __restrict__ be,
                               const float* __restrict__ stats, float* __restrict__ coef,
                               int C)
{
  int o = threadIdx.x;
  if (o < C) {
    const float invM = 1.0f / 65536.0f;   // B*N
    float mean = stats[o] * invM;
    float var  = stats[C + o] * invM - mean * mean;
    float a = g[o] / sqrtf(var + BN_EPS);
    float c = be[o] - mean * a;
    coef[o] = a;
    coef[C + o] = c;
  }
}

__global__ void zero_kernel(float* __restrict__ p, int n)
{
  int i = blockIdx.x * blockDim.x + threadIdx.x;
  if (i < n) p[i] = 0.0f;
}

// ---------------------------------------------------------------------------
__global__ __launch_bounds__(256) void final_kernel(
    const float* __restrict__ y1, const float* __restrict__ cf, float* __restrict__ out)
{
  const size_t total4 = (size_t)B_ * C2_ * N_ / 4;
  const size_t stride = (size_t)gridDim.x * blockDim.x;
  for (size_t f = (size_t)blockIdx.x * blockDim.x + threadIdx.x; f < total4; f += stride) {
    size_t base = f * 4;
    int p = (int)((base >> 13) & (C2_ - 1));   // 8192 floats per channel-row
    float a = cf[p], c = cf[C2_ + p];
    float4 v = *(const float4*)(y1 + base);
    float4 r;
    r.x = fmaxf(0.0f, fmaf(v.x, a, c));
    r.y = fmaxf(0.0f, fmaf(v.y, a, c));
    r.z = fmaxf(0.0f, fmaf(v.z, a, c));
    r.w = fmaxf(0.0f, fmaf(v.w, a, c));
    *(float4*)(out + base) = r;
  }
}

// ---------------------------------------------------------------------------
extern "C" void kernel_launch(void* const* d_in, const int* in_sizes, int n_in,
                              void* d_out, int out_size, void* d_ws, size_t ws_size,
                              hipStream_t stream)
{
  const float* xyz_sa     = (const float*)d_in[0];
  const float* xyz_now    = (const float*)d_in[1];
  const float* points_sa  = (const float*)d_in[2];
  const float* points_now = (const float*)d_in[3];
  const float* W0  = (const float*)d_in[4];
  const float* b0  = (const float*)d_in[5];
  const float* g0  = (const float*)d_in[6];
  const float* be0 = (const float*)d_in[7];
  const float* W1  = (const float*)d_in[8];
  const float* b1  = (const float*)d_in[9];
  const float* g1  = (const float*)d_in[10];
  const float* be1 = (const float*)d_in[11];
  // d_in[12] = k (always 3)

  float* ws      = (float*)d_ws;
  float* interpT = ws;                        // [B][N][D2] 64MB; later y1 [B][C2][N] 32MB
  float* y0      = ws + (size_t)16777216;     // [B][C1][N] 64MB
  float* pnT     = y0;                        // [B][S][D2] 16MB — dead before gemm1 writes y0
  float* y1      = ws;                        // reuse interpT region
  float* stats   = ws + (size_t)2 * 16777216; // 768 f
  float* coef    = stats + 768;               // 768 f
  float* out     = (float*)d_out;

  hipLaunchKernelGGL(zero_kernel, dim3(1), dim3(768), 0, stream, stats, 768);
  hipLaunchKernelGGL(transpose_kernel, dim3(S_ / 32, D2_ / 32, B_), dim3(256), 0, stream,
                     points_now, pnT);
  hipLaunchKernelGGL(knn_interp_kernel, dim3(N_ / 64, B_), dim3(256), 0, stream,
                     xyz_sa, xyz_now, pnT, interpT);
  hipLaunchKernelGGL(gemm1_kernel, dim3(N_ / 128, C1_ / 128, B_), dim3(256), 0, stream,
                     points_sa, interpT, W0, b0, y0, stats);
  hipLaunchKernelGGL(bn_coef_kernel, dim3(1), dim3(256), 0, stream,
                     g0, be0, stats, coef, C1_);
  hipLaunchKernelGGL(gemm2_kernel, dim3(N_ / 128, 1, B_), dim3(256), 0, stream,
                     y0, coef, W1, b1, y1, stats + 512);
  hipLaunchKernelGGL(bn_coef_kernel, dim3(1), dim3(128), 0, stream,
                     g1, be1, stats + 512, coef + 512, C2_);
  hipLaunchKernelGGL(final_kernel, dim3(2048), dim3(256), 0, stream,
                     y1, coef + 512, out);
}

// Round 3
// 469.546 us; speedup vs baseline: 1.5008x; 1.3822x over previous
//
#include <hip/hip_runtime.h>

#define B_ 8
#define N_ 8192
#define S_ 2048
#define D1_ 128
#define D2_ 256
#define C0_ 384
#define C1_ 256
#define C2_ 128
#define BN_EPS 1e-5f

typedef unsigned long long ull;

// branchless sorted-insert of key k into ascending top-3 (k0<=k1<=k2)
__device__ __forceinline__ void ins3(ull k, ull& k0, ull& k1, ull& k2) {
  ull t = k < k2 ? k : k2;
  ull u = k1 < t ? k1 : t;
  k2 = k1 < t ? t : k1;
  k1 = k0 < u ? u : k0;
  k0 = k0 < u ? k0 : u;
}

// ---------------------------------------------------------------------------
// K0: transpose points_now [B][D2][S] -> pnT [B][S][D2]
// ---------------------------------------------------------------------------
__global__ __launch_bounds__(256) void transpose_kernel(
    const float* __restrict__ in, float* __restrict__ out)
{
  __shared__ float tile[32][33];
  const int b  = blockIdx.z;
  const int s0 = blockIdx.x * 32;
  const int d0 = blockIdx.y * 32;
  const int tx = threadIdx.x & 31, ty = threadIdx.x >> 5;

  const float* inb = in + ((size_t)b * D2_ + d0) * S_ + s0;
  #pragma unroll
  for (int r = 0; r < 4; ++r) {
    int d = r * 8 + ty;
    tile[d][tx] = inb[(size_t)d * S_ + tx];
  }
  __syncthreads();
  float* outb = out + ((size_t)b * S_ + s0) * D2_ + d0;
  #pragma unroll
  for (int r = 0; r < 4; ++r) {
    int s = r * 8 + ty;
    outb[(size_t)s * D2_ + tx] = tile[tx][s];
  }
}

// ---------------------------------------------------------------------------
// K1: 3-NN + inverse-distance-weighted interpolation (fused).
// Block = 256 threads, 128 queries/block.
// Phase 1: branchless packed-key top-3; each thread owns 2 queries, 4 threads
//          split the 2048 candidates (512 each), butterfly-merge via shfl.
// Phase 2: one wave per 32 queries; 64 lanes x float4 = 256 channels,
//          coalesced reads from pnT [B][S][D2], coalesced writes interpT.
// ---------------------------------------------------------------------------
__global__ __launch_bounds__(256) void knn_interp_kernel(
    const float* __restrict__ xyz_sa, const float* __restrict__ xyz_now,
    const float* __restrict__ pnT, float* __restrict__ interpT)
{
  __shared__ float4 sp[S_];          // (px,py,pz,|p|^2) per candidate
  __shared__ int   s_idx[128][3];
  __shared__ float s_w[128][3];

  const int b  = blockIdx.y;
  const int n0 = blockIdx.x * 128;

  // stage candidates (with precomputed squared norm)
  const float* xb = xyz_now + (size_t)b * 3 * S_;
  for (int i = threadIdx.x; i < S_; i += 256) {
    float px = xb[i], py = xb[S_ + i], pz = xb[2 * S_ + i];
    sp[i] = make_float4(px, py, pz, px * px + py * py + pz * pz);
  }
  __syncthreads();

  const int qp = threadIdx.x >> 2;   // query pair 0..63
  const int t  = threadIdx.x & 3;    // candidate sub-scanner
  const int nA = n0 + qp * 2;
  const int nB = nA + 1;

  const float* xq = xyz_sa + (size_t)b * 3 * N_;
  const float qxA = xq[nA], qyA = xq[N_ + nA], qzA = xq[2 * N_ + nA];
  const float qxB = xq[nB], qyB = xq[N_ + nB], qzB = xq[2 * N_ + nB];
  const float qqA = qxA * qxA + qyA * qyA + qzA * qzA;
  const float qqB = qxB * qxB + qyB * qyB + qzB * qzB;

  ull a0 = ~0ull, a1 = ~0ull, a2 = ~0ull;
  ull b0k = ~0ull, b1k = ~0ull, b2k = ~0ull;

  #pragma unroll 2
  for (int it = 0; it < S_ / 4; ++it) {
    int s = (it << 2) | t;
    float4 p = sp[s];
    // query A (distance arithmetic identical to prior passing kernel)
    {
      float dot = qxA * p.x + qyA * p.y + qzA * p.z;
      float d = qqA - 2.0f * dot + p.w;
      unsigned int bits = __float_as_uint(d);
      unsigned int u = bits ^ (0x80000000u | (unsigned int)((int)bits >> 31));
      ull k = ((ull)u << 32) | (unsigned int)s;
      ins3(k, a0, a1, a2);
    }
    // query B
    {
      float dot = qxB * p.x + qyB * p.y + qzB * p.z;
      float d = qqB - 2.0f * dot + p.w;
      unsigned int bits = __float_as_uint(d);
      unsigned int u = bits ^ (0x80000000u | (unsigned int)((int)bits >> 31));
      ull k = ((ull)u << 32) | (unsigned int)s;
      ins3(k, b0k, b1k, b2k);
    }
  }

  // merge the 4 scanners via shuffle butterfly
  #pragma unroll
  for (int m = 1; m <= 2; m <<= 1) {
    ull o0 = __shfl_xor(a0, m), o1 = __shfl_xor(a1, m), o2 = __shfl_xor(a2, m);
    ins3(o0, a0, a1, a2); ins3(o1, a0, a1, a2); ins3(o2, a0, a1, a2);
    ull p0 = __shfl_xor(b0k, m), p1 = __shfl_xor(b1k, m), p2 = __shfl_xor(b2k, m);
    ins3(p0, b0k, b1k, b2k); ins3(p1, b0k, b1k, b2k); ins3(p2, b0k, b1k, b2k);
  }

  if (t == 0) {
    #pragma unroll
    for (int w = 0; w < 2; ++w) {
      ull k0 = w ? b0k : a0, k1 = w ? b1k : a1, k2 = w ? b2k : a2;
      float d0, d1, d2;
      {
        unsigned int u = (unsigned int)(k0 >> 32);
        d0 = __uint_as_float(u ^ (0x80000000u | ~(unsigned int)((int)u >> 31)));
      }
      {
        unsigned int u = (unsigned int)(k1 >> 32);
        d1 = __uint_as_float(u ^ (0x80000000u | ~(unsigned int)((int)u >> 31)));
      }
      {
        unsigned int u = (unsigned int)(k2 >> 32);
        d2 = __uint_as_float(u ^ (0x80000000u | ~(unsigned int)((int)u >> 31)));
      }
      float r0 = 1.0f / (d0 + 1e-8f);
      float r1 = 1.0f / (d1 + 1e-8f);
      float r2 = 1.0f / (d2 + 1e-8f);
      float rs = 1.0f / (r0 + r1 + r2);
      int qi = qp * 2 + w;
      s_idx[qi][0] = (int)(k0 & 0xFFFFFFFFu);
      s_idx[qi][1] = (int)(k1 & 0xFFFFFFFFu);
      s_idx[qi][2] = (int)(k2 & 0xFFFFFFFFu);
      s_w[qi][0] = r0 * rs; s_w[qi][1] = r1 * rs; s_w[qi][2] = r2 * rs;
    }
  }
  __syncthreads();

  // Phase 2: wave-per-query gather, fully coalesced.
  const int wave = threadIdx.x >> 6;  // 0..3
  const int lane = threadIdx.x & 63;
  const float* pb = pnT + (size_t)b * S_ * D2_;
  float* ob = interpT + ((size_t)b * N_ + n0) * D2_;
  #pragma unroll 2
  for (int i = 0; i < 32; ++i) {
    const int qi = wave * 32 + i;
    const int j0 = s_idx[qi][0], j1 = s_idx[qi][1], j2 = s_idx[qi][2];
    const float w0 = s_w[qi][0], w1 = s_w[qi][1], w2 = s_w[qi][2];
    float4 f0 = *(const float4*)(pb + (size_t)j0 * D2_ + lane * 4);
    float4 f1 = *(const float4*)(pb + (size_t)j1 * D2_ + lane * 4);
    float4 f2 = *(const float4*)(pb + (size_t)j2 * D2_ + lane * 4);
    float4 r;
    r.x = w0 * f0.x + w1 * f1.x + w2 * f2.x;
    r.y = w0 * f0.y + w1 * f1.y + w2 * f2.y;
    r.z = w0 * f0.z + w1 * f1.z + w2 * f2.z;
    r.w = w0 * f0.w + w1 * f1.w + w2 * f2.w;
    *(float4*)(ob + (size_t)qi * D2_ + lane * 4) = r;
  }
}

// ---------------------------------------------------------------------------
// K2: GEMM1  y0[b,o,n] = W0[o,:] . x[b,:,n] + b0[o]
// x = concat(points_sa [D1][N], interpT [N][D2] transposed on load)
// ---------------------------------------------------------------------------
__global__ __launch_bounds__(256) void gemm1_kernel(
    const float* __restrict__ points_sa, const float* __restrict__ interpT,
    const float* __restrict__ W0, const float* __restrict__ b0,
    float* __restrict__ y0, float* __restrict__ stats)
{
  __shared__ float As[32][132];   // [k][o], padded
  __shared__ float Bs[32][132];   // [k][n], padded (transposed writes hit it)

  const int b  = blockIdx.z;
  const int n0 = blockIdx.x * 128;
  const int o0 = blockIdx.y * 128;
  const int tid = threadIdx.x;
  const int tx = tid & 15, ty = tid >> 4;

  float acc[8][8];
  #pragma unroll
  for (int i = 0; i < 8; ++i)
    #pragma unroll
    for (int j = 0; j < 8; ++j) acc[i][j] = 0.0f;

  for (int kt = 0; kt < C0_; kt += 32) {
    {
      const int row8 = tid >> 3;
      const int c4 = (tid & 7) << 2;
      #pragma unroll
      for (int r = 0; r < 4; ++r) {
        int o = r * 32 + row8;
        float4 v = *(const float4*)(W0 + (size_t)(o0 + o) * C0_ + kt + c4);
        As[c4 + 0][o] = v.x; As[c4 + 1][o] = v.y;
        As[c4 + 2][o] = v.z; As[c4 + 3][o] = v.w;
      }
    }
    if (kt < D1_) {
      const float* src = points_sa + ((size_t)b * D1_ + kt) * N_ + n0;
      const int rr = tid >> 5;
      const int c4 = (tid & 31) << 2;
      #pragma unroll
      for (int r = 0; r < 4; ++r) {
        int c = r * 8 + rr;
        *(float4*)&Bs[c][c4] = *(const float4*)(src + (size_t)c * N_ + c4);
      }
    } else {
      const float* srcT = interpT + ((size_t)b * N_ + n0) * D2_ + (kt - D1_);
      const int cc = (tid & 7) << 2;     // k-chunk
      const int nb = tid >> 3;           // 0..31
      #pragma unroll
      for (int r = 0; r < 4; ++r) {
        int nl = r * 32 + nb;
        float4 v = *(const float4*)(srcT + (size_t)nl * D2_ + cc);
        Bs[cc + 0][nl] = v.x; Bs[cc + 1][nl] = v.y;
        Bs[cc + 2][nl] = v.z; Bs[cc + 3][nl] = v.w;
      }
    }
    __syncthreads();
    #pragma unroll 4
    for (int k = 0; k < 32; ++k) {
      float a[8], bb[8];
      *(float4*)&a[0]  = *(const float4*)&As[k][ty * 8];
      *(float4*)&a[4]  = *(const float4*)&As[k][ty * 8 + 4];
      *(float4*)&bb[0] = *(const float4*)&Bs[k][tx * 8];
      *(float4*)&bb[4] = *(const float4*)&Bs[k][tx * 8 + 4];
      #pragma unroll
      for (int i = 0; i < 8; ++i)
        #pragma unroll
        for (int j = 0; j < 8; ++j)
          acc[i][j] = fmaf(a[i], bb[j], acc[i][j]);
    }
    __syncthreads();
  }

  float* outb = y0 + ((size_t)b * C1_ + o0) * N_ + n0;
  #pragma unroll
  for (int i = 0; i < 8; ++i) {
    const int o = ty * 8 + i;
    const float bias = b0[o0 + o];
    float s1 = 0.0f, s2 = 0.0f;
    float v[8];
    #pragma unroll
    for (int j = 0; j < 8; ++j) {
      float y = acc[i][j] + bias;
      v[j] = y; s1 += y; s2 += y * y;
    }
    *(float4*)(outb + (size_t)o * N_ + tx * 8)     = make_float4(v[0], v[1], v[2], v[3]);
    *(float4*)(outb + (size_t)o * N_ + tx * 8 + 4) = make_float4(v[4], v[5], v[6], v[7]);
    #pragma unroll
    for (int m = 1; m < 16; m <<= 1) { s1 += __shfl_xor(s1, m); s2 += __shfl_xor(s2, m); }
    if (tx == 0) {
      atomicAdd(&stats[o0 + o], s1);
      atomicAdd(&stats[C1_ + o0 + o], s2);
    }
  }
}

// ---------------------------------------------------------------------------
// K4: GEMM2  y1[b,p,n] = W1[p,:] . relu(bn0(y0[b,:,n])) + b1[p]
// ---------------------------------------------------------------------------
__global__ __launch_bounds__(256) void gemm2_kernel(
    const float* __restrict__ y0, const float* __restrict__ coef,
    const float* __restrict__ W1, const float* __restrict__ b1,
    float* __restrict__ y1, float* __restrict__ stats)
{
  __shared__ float As[32][132];
  __shared__ float Bs[32][128];

  const int b  = blockIdx.z;
  const int n0 = blockIdx.x * 128;
  const int tid = threadIdx.x;
  const int tx = tid & 15, ty = tid >> 4;

  float acc[8][8];
  #pragma unroll
  for (int i = 0; i < 8; ++i)
    #pragma unroll
    for (int j = 0; j < 8; ++j) acc[i][j] = 0.0f;

  for (int kt = 0; kt < C1_; kt += 32) {
    {
      const int row8 = tid >> 3;
      const int c4 = (tid & 7) << 2;
      #pragma unroll
      for (int r = 0; r < 4; ++r) {
        int o = r * 32 + row8;
        float4 v = *(const float4*)(W1 + (size_t)o * C1_ + kt + c4);
        As[c4 + 0][o] = v.x; As[c4 + 1][o] = v.y;
        As[c4 + 2][o] = v.z; As[c4 + 3][o] = v.w;
      }
    }
    {
      const int rr = tid >> 5;
      const int c4 = (tid & 31) << 2;
      #pragma unroll
      for (int r = 0; r < 4; ++r) {
        int c = r * 8 + rr;
        int cg = kt + c;
        float aa = coef[cg], cc = coef[C1_ + cg];
        const float* src = y0 + ((size_t)b * C1_ + cg) * N_ + n0;
        float4 v = *(const float4*)(src + c4);
        v.x = fmaxf(0.0f, fmaf(v.x, aa, cc));
        v.y = fmaxf(0.0f, fmaf(v.y, aa, cc));
        v.z = fmaxf(0.0f, fmaf(v.z, aa, cc));
        v.w = fmaxf(0.0f, fmaf(v.w, aa, cc));
        *(float4*)&Bs[c][c4] = v;
      }
    }
    __syncthreads();
    #pragma unroll 4
    for (int k = 0; k < 32; ++k) {
      float a[8], bb[8];
      *(float4*)&a[0]  = *(const float4*)&As[k][ty * 8];
      *(float4*)&a[4]  = *(const float4*)&As[k][ty * 8 + 4];
      *(float4*)&bb[0] = *(const float4*)&Bs[k][tx * 8];
      *(float4*)&bb[4] = *(const float4*)&Bs[k][tx * 8 + 4];
      #pragma unroll
      for (int i = 0; i < 8; ++i)
        #pragma unroll
        for (int j = 0; j < 8; ++j)
          acc[i][j] = fmaf(a[i], bb[j], acc[i][j]);
    }
    __syncthreads();
  }

  float* outb = y1 + ((size_t)b * C2_) * N_ + n0;
  #pragma unroll
  for (int i = 0; i < 8; ++i) {
    const int o = ty * 8 + i;
    const float bias = b1[o];
    float s1 = 0.0f, s2 = 0.0f;
    float v[8];
    #pragma unroll
    for (int j = 0; j < 8; ++j) {
      float y = acc[i][j] + bias;
      v[j] = y; s1 += y; s2 += y * y;
    }
    *(float4*)(outb + (size_t)o * N_ + tx * 8)     = make_float4(v[0], v[1], v[2], v[3]);
    *(float4*)(outb + (size_t)o * N_ + tx * 8 + 4) = make_float4(v[4], v[5], v[6], v[7]);
    #pragma unroll
    for (int m = 1; m < 16; m <<= 1) { s1 += __shfl_xor(s1, m); s2 += __shfl_xor(s2, m); }
    if (tx == 0) {
      atomicAdd(&stats[o], s1);
      atomicAdd(&stats[C2_ + o], s2);
    }
  }
}

// ---------------------------------------------------------------------------
__global__ void bn_coef_kernel(const float* __restrict__ g, const float* __restrict__ be,
                               const float* __restrict__ stats, float* __restrict__ coef,
                               int C)
{
  int o = threadIdx.x;
  if (o < C) {
    const float invM = 1.0f / 65536.0f;   // B*N
    float mean = stats[o] * invM;
    float var  = stats[C + o] * invM - mean * mean;
    float a = g[o] / sqrtf(var + BN_EPS);
    float c = be[o] - mean * a;
    coef[o] = a;
    coef[C + o] = c;
  }
}

__global__ void zero_kernel(float* __restrict__ p, int n)
{
  int i = blockIdx.x * blockDim.x + threadIdx.x;
  if (i < n) p[i] = 0.0f;
}

// ---------------------------------------------------------------------------
__global__ __launch_bounds__(256) void final_kernel(
    const float* __restrict__ y1, const float* __restrict__ cf, float* __restrict__ out)
{
  const size_t total4 = (size_t)B_ * C2_ * N_ / 4;
  const size_t stride = (size_t)gridDim.x * blockDim.x;
  for (size_t f = (size_t)blockIdx.x * blockDim.x + threadIdx.x; f < total4; f += stride) {
    size_t base = f * 4;
    int p = (int)((base >> 13) & (C2_ - 1));   // 8192 floats per channel-row
    float a = cf[p], c = cf[C2_ + p];
    float4 v = *(const float4*)(y1 + base);
    float4 r;
    r.x = fmaxf(0.0f, fmaf(v.x, a, c));
    r.y = fmaxf(0.0f, fmaf(v.y, a, c));
    r.z = fmaxf(0.0f, fmaf(v.z, a, c));
    r.w = fmaxf(0.0f, fmaf(v.w, a, c));
    *(float4*)(out + base) = r;
  }
}

// ---------------------------------------------------------------------------
extern "C" void kernel_launch(void* const* d_in, const int* in_sizes, int n_in,
                              void* d_out, int out_size, void* d_ws, size_t ws_size,
                              hipStream_t stream)
{
  const float* xyz_sa     = (const float*)d_in[0];
  const float* xyz_now    = (const float*)d_in[1];
  const float* points_sa  = (const float*)d_in[2];
  const float* points_now = (const float*)d_in[3];
  const float* W0  = (const float*)d_in[4];
  const float* b0  = (const float*)d_in[5];
  const float* g0  = (const float*)d_in[6];
  const float* be0 = (const float*)d_in[7];
  const float* W1  = (const float*)d_in[8];
  const float* b1  = (const float*)d_in[9];
  const float* g1  = (const float*)d_in[10];
  const float* be1 = (const float*)d_in[11];
  // d_in[12] = k (always 3)

  float* ws      = (float*)d_ws;
  float* interpT = ws;                        // [B][N][D2] 64MB; later y1 region
  float* y0      = ws + (size_t)16777216;     // [B][C1][N] 64MB
  float* pnT     = y0;                        // [B][S][D2] 16MB — dead before gemm1 writes y0
  float* y1      = ws;                        // reuse interpT region
  float* stats   = ws + (size_t)2 * 16777216; // 768 f
  float* coef    = stats + 768;               // 768 f
  float* out     = (float*)d_out;

  hipLaunchKernelGGL(zero_kernel, dim3(1), dim3(768), 0, stream, stats, 768);
  hipLaunchKernelGGL(transpose_kernel, dim3(S_ / 32, D2_ / 32, B_), dim3(256), 0, stream,
                     points_now, pnT);
  hipLaunchKernelGGL(knn_interp_kernel, dim3(N_ / 128, B_), dim3(256), 0, stream,
                     xyz_sa, xyz_now, pnT, interpT);
  hipLaunchKernelGGL(gemm1_kernel, dim3(N_ / 128, C1_ / 128, B_), dim3(256), 0, stream,
                     points_sa, interpT, W0, b0, y0, stats);
  hipLaunchKernelGGL(bn_coef_kernel, dim3(1), dim3(256), 0, stream,
                     g0, be0, stats, coef, C1_);
  hipLaunchKernelGGL(gemm2_kernel, dim3(N_ / 128, 1, B_), dim3(256), 0, stream,
                     y0, coef, W1, b1, y1, stats + 512);
  hipLaunchKernelGGL(bn_coef_kernel, dim3(1), dim3(128), 0, stream,
                     g1, be1, stats + 512, coef + 512, C2_);
  hipLaunchKernelGGL(final_kernel, dim3(2048), dim3(256), 0, stream,
                     y1, coef + 512, out);
}

// Round 4
// 407.370 us; speedup vs baseline: 1.7299x; 1.1526x over previous
//
#include <hip/hip_runtime.h>

#define B_ 8
#define N_ 8192
#define S_ 2048
#define D1_ 128
#define D2_ 256
#define C0_ 384
#define C1_ 256
#define C2_ 128
#define BN_EPS 1e-5f

typedef unsigned long long ull;
typedef unsigned short u16;
typedef __bf16 bf16x8 __attribute__((ext_vector_type(8)));
typedef float f32x4 __attribute__((ext_vector_type(4)));
typedef short short8_ __attribute__((ext_vector_type(8)));

__device__ __forceinline__ u16 f2bf(float x) {
  unsigned int u = __float_as_uint(x);
  unsigned int r = u + 0x7fffu + ((u >> 16) & 1u);
  return (u16)(r >> 16);
}
__device__ __forceinline__ float bf2f(u16 h) {
  return __uint_as_float(((unsigned int)h) << 16);
}

// branchless sorted-insert of key k into ascending top-3 (k0<=k1<=k2)
__device__ __forceinline__ void ins3(ull k, ull& k0, ull& k1, ull& k2) {
  ull t = k < k2 ? k : k2;
  ull u = k1 < t ? k1 : t;
  k2 = k1 < t ? t : k1;
  k1 = k0 < u ? u : k0;
  k0 = k0 < u ? k0 : u;
}

// ---------------------------------------------------------------------------
// fp32 -> bf16 convert (for weights)
// ---------------------------------------------------------------------------
__global__ void cvt_bf16_kernel(const float* __restrict__ src, u16* __restrict__ dst, int n)
{
  int i = blockIdx.x * blockDim.x + threadIdx.x;
  if (i < n) dst[i] = f2bf(src[i]);
}

// ---------------------------------------------------------------------------
// transpose points_now [B][D2][S] -> pnT [B][S][D2]  (fp32, for knn gather)
// ---------------------------------------------------------------------------
__global__ __launch_bounds__(256) void transpose_kernel(
    const float* __restrict__ in, float* __restrict__ out)
{
  __shared__ float tile[32][33];
  const int b  = blockIdx.z;
  const int s0 = blockIdx.x * 32;
  const int d0 = blockIdx.y * 32;
  const int tx = threadIdx.x & 31, ty = threadIdx.x >> 5;

  const float* inb = in + ((size_t)b * D2_ + d0) * S_ + s0;
  #pragma unroll
  for (int r = 0; r < 4; ++r) {
    int d = r * 8 + ty;
    tile[d][tx] = inb[(size_t)d * S_ + tx];
  }
  __syncthreads();
  float* outb = out + ((size_t)b * S_ + s0) * D2_ + d0;
  #pragma unroll
  for (int r = 0; r < 4; ++r) {
    int s = r * 8 + ty;
    outb[(size_t)s * D2_ + tx] = tile[tx][s];
  }
}

// ---------------------------------------------------------------------------
// transpose+convert points_sa [B][D1][N] f32 -> psaT [B][N][D1] bf16
// ---------------------------------------------------------------------------
__global__ __launch_bounds__(256) void psaT_kernel(
    const float* __restrict__ in, u16* __restrict__ out)
{
  __shared__ float tile[32][33];
  const int b  = blockIdx.z;
  const int n0 = blockIdx.x * 32;
  const int d0 = blockIdx.y * 32;
  const int tx = threadIdx.x & 31, ty = threadIdx.x >> 5;

  const float* inb = in + ((size_t)b * D1_ + d0) * N_ + n0;
  #pragma unroll
  for (int r = 0; r < 4; ++r) {
    int d = r * 8 + ty;
    tile[d][tx] = inb[(size_t)d * N_ + tx];
  }
  __syncthreads();
  u16* outb = out + ((size_t)b * N_ + n0) * D1_ + d0;
  #pragma unroll
  for (int r = 0; r < 4; ++r) {
    int n = r * 8 + ty;
    outb[(size_t)n * D1_ + tx] = f2bf(tile[tx][n]);
  }
}

// ---------------------------------------------------------------------------
// K1: 3-NN + interpolation. 128 queries/block.
// Phase 1: 4 queries/thread, 8 scanners/query (256 cands each) -> ILP x4.
// Phase 2: wave-per-query gather; writes interpT [B][N][D2] bf16.
// ---------------------------------------------------------------------------
__global__ __launch_bounds__(256) void knn_interp_kernel(
    const float* __restrict__ xyz_sa, const float* __restrict__ xyz_now,
    const float* __restrict__ pnT, u16* __restrict__ interpT)
{
  __shared__ float4 sp[S_];
  __shared__ int   s_idx[128][3];
  __shared__ float s_w[128][3];

  const int b  = blockIdx.y;
  const int n0 = blockIdx.x * 128;

  const float* xb = xyz_now + (size_t)b * 3 * S_;
  for (int i = threadIdx.x; i < S_; i += 256) {
    float px = xb[i], py = xb[S_ + i], pz = xb[2 * S_ + i];
    sp[i] = make_float4(px, py, pz, px * px + py * py + pz * pz);
  }
  __syncthreads();

  const int qg = threadIdx.x >> 3;   // 0..31 query group (4 queries)
  const int t  = threadIdx.x & 7;    // scanner 0..7
  const int nb = n0 + qg * 4;

  const float* xq = xyz_sa + (size_t)b * 3 * N_;
  float qx[4], qy[4], qz[4], qq[4];
  #pragma unroll
  for (int w = 0; w < 4; ++w) {
    int n = nb + w;
    qx[w] = xq[n]; qy[w] = xq[N_ + n]; qz[w] = xq[2 * N_ + n];
    qq[w] = qx[w] * qx[w] + qy[w] * qy[w] + qz[w] * qz[w];
  }

  ull K0[4], K1[4], K2[4];
  #pragma unroll
  for (int w = 0; w < 4; ++w) { K0[w] = ~0ull; K1[w] = ~0ull; K2[w] = ~0ull; }

  #pragma unroll 2
  for (int it = 0; it < S_ / 8; ++it) {
    int s = (it << 3) | t;
    float4 p = sp[s];
    #pragma unroll
    for (int w = 0; w < 4; ++w) {
      float dot = qx[w] * p.x + qy[w] * p.y + qz[w] * p.z;
      float d = qq[w] - 2.0f * dot + p.w;
      unsigned int bits = __float_as_uint(d);
      unsigned int u = bits ^ (0x80000000u | (unsigned int)((int)bits >> 31));
      ull k = ((ull)u << 32) | (unsigned int)s;
      ins3(k, K0[w], K1[w], K2[w]);
    }
  }

  // merge the 8 scanners via shuffle butterfly (masks stay in 8-lane group)
  #pragma unroll
  for (int m = 1; m <= 4; m <<= 1) {
    #pragma unroll
    for (int w = 0; w < 4; ++w) {
      ull o0 = __shfl_xor(K0[w], m), o1 = __shfl_xor(K1[w], m), o2 = __shfl_xor(K2[w], m);
      ins3(o0, K0[w], K1[w], K2[w]);
      ins3(o1, K0[w], K1[w], K2[w]);
      ins3(o2, K0[w], K1[w], K2[w]);
    }
  }

  if (t == 0) {
    #pragma unroll
    for (int w = 0; w < 4; ++w) {
      unsigned int u0 = (unsigned int)(K0[w] >> 32);
      unsigned int u1 = (unsigned int)(K1[w] >> 32);
      unsigned int u2 = (unsigned int)(K2[w] >> 32);
      float d0 = __uint_as_float(u0 ^ (0x80000000u | ~(unsigned int)((int)u0 >> 31)));
      float d1 = __uint_as_float(u1 ^ (0x80000000u | ~(unsigned int)((int)u1 >> 31)));
      float d2 = __uint_as_float(u2 ^ (0x80000000u | ~(unsigned int)((int)u2 >> 31)));
      float r0 = 1.0f / (d0 + 1e-8f);
      float r1 = 1.0f / (d1 + 1e-8f);
      float r2 = 1.0f / (d2 + 1e-8f);
      float rs = 1.0f / (r0 + r1 + r2);
      int qi = qg * 4 + w;
      s_idx[qi][0] = (int)(K0[w] & 0xFFFFFFFFu);
      s_idx[qi][1] = (int)(K1[w] & 0xFFFFFFFFu);
      s_idx[qi][2] = (int)(K2[w] & 0xFFFFFFFFu);
      s_w[qi][0] = r0 * rs; s_w[qi][1] = r1 * rs; s_w[qi][2] = r2 * rs;
    }
  }
  __syncthreads();

  // Phase 2: wave-per-query gather, coalesced; bf16 output.
  const int wave = threadIdx.x >> 6;
  const int lane = threadIdx.x & 63;
  const float* pb = pnT + (size_t)b * S_ * D2_;
  u16* ob = interpT + ((size_t)b * N_ + n0) * D2_;
  #pragma unroll 2
  for (int i = 0; i < 32; ++i) {
    const int qi = wave * 32 + i;
    const int j0 = s_idx[qi][0], j1 = s_idx[qi][1], j2 = s_idx[qi][2];
    const float w0 = s_w[qi][0], w1 = s_w[qi][1], w2 = s_w[qi][2];
    float4 f0 = *(const float4*)(pb + (size_t)j0 * D2_ + lane * 4);
    float4 f1 = *(const float4*)(pb + (size_t)j1 * D2_ + lane * 4);
    float4 f2 = *(const float4*)(pb + (size_t)j2 * D2_ + lane * 4);
    float rx = w0 * f0.x + w1 * f1.x + w2 * f2.x;
    float ry = w0 * f0.y + w1 * f1.y + w2 * f2.y;
    float rz = w0 * f0.z + w1 * f1.z + w2 * f2.z;
    float rw = w0 * f0.w + w1 * f1.w + w2 * f2.w;
    unsigned int lo = (unsigned int)f2bf(rx) | ((unsigned int)f2bf(ry) << 16);
    unsigned int hi = (unsigned int)f2bf(rz) | ((unsigned int)f2bf(rw) << 16);
    *(uint2*)(ob + (size_t)qi * D2_ + lane * 4) = make_uint2(lo, hi);
  }
}

// ---------------------------------------------------------------------------
// GEMM1 (MFMA bf16): y0[b,n,o] = W0[o,:] . x[b,:,n] + b0[o]
// A = W0b [256][384] bf16; B rows from psaT [N][128] / interpT [N][256].
// Block 256 thr (4 waves), tile 128o x 128n, BK=32. Wave = 64o x 64n.
// Output y0b [B][N][C1] bf16 + per-channel sum/sumsq atomics.
// ---------------------------------------------------------------------------
__global__ __launch_bounds__(256) void gemm1_mfma_kernel(
    const u16* __restrict__ psaT, const u16* __restrict__ interpT,
    const u16* __restrict__ W0b, const float* __restrict__ b0,
    u16* __restrict__ y0b, float* __restrict__ stats)
{
  __shared__ u16 As[128][40];   // [o][k] 80B rows
  __shared__ u16 Bs[128][40];   // [n][k]

  const int bz = blockIdx.z;
  const int n0 = blockIdx.x * 128;
  const int o0 = blockIdx.y * 128;
  const int tid = threadIdx.x;
  const int wid = tid >> 6, lane = tid & 63;
  const int wo = wid & 1, wn = wid >> 1;
  const int m = lane & 15, g = lane >> 4;

  f32x4 acc[4][4];
  #pragma unroll
  for (int i = 0; i < 4; ++i)
    #pragma unroll
    for (int j = 0; j < 4; ++j) acc[i][j] = (f32x4){0.f, 0.f, 0.f, 0.f};

  for (int kt = 0; kt < C0_; kt += 32) {
    #pragma unroll
    for (int c = tid; c < 512; c += 256) {
      const int row = c >> 2, cb = (c & 3) << 3;
      *(uint4*)&As[row][cb] =
          *(const uint4*)(W0b + (size_t)(o0 + row) * C0_ + kt + cb);
      const u16* bsrc = (kt < D1_)
          ? psaT    + (size_t)(bz * N_ + n0 + row) * D1_ + kt + cb
          : interpT + (size_t)(bz * N_ + n0 + row) * D2_ + (kt - D1_) + cb;
      *(uint4*)&Bs[row][cb] = *(const uint4*)bsrc;
    }
    __syncthreads();

    bf16x8 af[4], bfv[4];
    #pragma unroll
    for (int f = 0; f < 4; ++f)
      af[f] = __builtin_bit_cast(bf16x8, *(const short8_*)&As[wo * 64 + f * 16 + m][g * 8]);
    #pragma unroll
    for (int f = 0; f < 4; ++f)
      bfv[f] = __builtin_bit_cast(bf16x8, *(const short8_*)&Bs[wn * 64 + f * 16 + m][g * 8]);
    #pragma unroll
    for (int i = 0; i < 4; ++i)
      #pragma unroll
      for (int j = 0; j < 4; ++j)
        acc[i][j] = __builtin_amdgcn_mfma_f32_16x16x32_bf16(af[i], bfv[j], acc[i][j], 0, 0, 0);
    __syncthreads();
  }

  // epilogue: bias, bf16 store to y0b [B][N][C1], stats
  #pragma unroll
  for (int of = 0; of < 4; ++of) {
    const int ob = o0 + wo * 64 + of * 16 + g * 4;
    float bias[4], s1[4], s2[4];
    #pragma unroll
    for (int r = 0; r < 4; ++r) { bias[r] = b0[ob + r]; s1[r] = 0.f; s2[r] = 0.f; }
    #pragma unroll
    for (int nf = 0; nf < 4; ++nf) {
      const int n = n0 + wn * 64 + nf * 16 + m;
      float y[4];
      #pragma unroll
      for (int r = 0; r < 4; ++r) {
        y[r] = acc[of][nf][r] + bias[r];
        s1[r] += y[r]; s2[r] += y[r] * y[r];
      }
      unsigned int lo = (unsigned int)f2bf(y[0]) | ((unsigned int)f2bf(y[1]) << 16);
      unsigned int hi = (unsigned int)f2bf(y[2]) | ((unsigned int)f2bf(y[3]) << 16);
      *(uint2*)(y0b + (size_t)(bz * N_ + n) * C1_ + ob) = make_uint2(lo, hi);
    }
    #pragma unroll
    for (int mk = 1; mk < 16; mk <<= 1)
      #pragma unroll
      for (int r = 0; r < 4; ++r) {
        s1[r] += __shfl_xor(s1[r], mk);
        s2[r] += __shfl_xor(s2[r], mk);
      }
    if (m == 0) {
      #pragma unroll
      for (int r = 0; r < 4; ++r) {
        atomicAdd(&stats[ob + r], s1[r]);
        atomicAdd(&stats[C1_ + ob + r], s2[r]);
      }
    }
  }
}

// ---------------------------------------------------------------------------
// GEMM2 (MFMA bf16): y1[b,p,n] = W1[p,:] . relu(bn0(y0[b,:,n])) + b1[p]
// BN0+ReLU applied during B-tile staging from y0b [B][N][C1] bf16.
// Output y1 fp32 [B][C2][N] + stats.
// ---------------------------------------------------------------------------
__global__ __launch_bounds__(256) void gemm2_mfma_kernel(
    const u16* __restrict__ y0b, const float* __restrict__ coef,
    const u16* __restrict__ W1b, const float* __restrict__ b1,
    float* __restrict__ y1, float* __restrict__ stats)
{
  __shared__ u16 As[128][40];
  __shared__ u16 Bs[128][40];

  const int bz = blockIdx.z;
  const int n0 = blockIdx.x * 128;
  const int tid = threadIdx.x;
  const int wid = tid >> 6, lane = tid & 63;
  const int wo = wid & 1, wn = wid >> 1;
  const int m = lane & 15, g = lane >> 4;

  f32x4 acc[4][4];
  #pragma unroll
  for (int i = 0; i < 4; ++i)
    #pragma unroll
    for (int j = 0; j < 4; ++j) acc[i][j] = (f32x4){0.f, 0.f, 0.f, 0.f};

  for (int kt = 0; kt < C1_; kt += 32) {
    #pragma unroll
    for (int c = tid; c < 512; c += 256) {
      const int row = c >> 2, cb = (c & 3) << 3;
      *(uint4*)&As[row][cb] =
          *(const uint4*)(W1b + (size_t)row * C1_ + kt + cb);
      const int cg = kt + cb;
      uint4 v = *(const uint4*)(y0b + (size_t)(bz * N_ + n0 + row) * C1_ + cg);
      float4 a0 = *(const float4*)(coef + cg);
      float4 a1 = *(const float4*)(coef + cg + 4);
      float4 c0 = *(const float4*)(coef + C1_ + cg);
      float4 c1 = *(const float4*)(coef + C1_ + cg + 4);
      float f0 = fmaxf(0.f, fmaf(bf2f((u16)(v.x & 0xffff)), a0.x, c0.x));
      float f1 = fmaxf(0.f, fmaf(bf2f((u16)(v.x >> 16)),   a0.y, c0.y));
      float f2 = fmaxf(0.f, fmaf(bf2f((u16)(v.y & 0xffff)), a0.z, c0.z));
      float f3 = fmaxf(0.f, fmaf(bf2f((u16)(v.y >> 16)),   a0.w, c0.w));
      float f4 = fmaxf(0.f, fmaf(bf2f((u16)(v.z & 0xffff)), a1.x, c1.x));
      float f5 = fmaxf(0.f, fmaf(bf2f((u16)(v.z >> 16)),   a1.y, c1.y));
      float f6 = fmaxf(0.f, fmaf(bf2f((u16)(v.w & 0xffff)), a1.z, c1.z));
      float f7 = fmaxf(0.f, fmaf(bf2f((u16)(v.w >> 16)),   a1.w, c1.w));
      uint4 o;
      o.x = (unsigned int)f2bf(f0) | ((unsigned int)f2bf(f1) << 16);
      o.y = (unsigned int)f2bf(f2) | ((unsigned int)f2bf(f3) << 16);
      o.z = (unsigned int)f2bf(f4) | ((unsigned int)f2bf(f5) << 16);
      o.w = (unsigned int)f2bf(f6) | ((unsigned int)f2bf(f7) << 16);
      *(uint4*)&Bs[row][cb] = o;
    }
    __syncthreads();

    bf16x8 af[4], bfv[4];
    #pragma unroll
    for (int f = 0; f < 4; ++f)
      af[f] = __builtin_bit_cast(bf16x8, *(const short8_*)&As[wo * 64 + f * 16 + m][g * 8]);
    #pragma unroll
    for (int f = 0; f < 4; ++f)
      bfv[f] = __builtin_bit_cast(bf16x8, *(const short8_*)&Bs[wn * 64 + f * 16 + m][g * 8]);
    #pragma unroll
    for (int i = 0; i < 4; ++i)
      #pragma unroll
      for (int j = 0; j < 4; ++j)
        acc[i][j] = __builtin_amdgcn_mfma_f32_16x16x32_bf16(af[i], bfv[j], acc[i][j], 0, 0, 0);
    __syncthreads();
  }

  #pragma unroll
  for (int of = 0; of < 4; ++of) {
    const int pb = wo * 64 + of * 16 + g * 4;
    float bias[4], s1[4], s2[4];
    #pragma unroll
    for (int r = 0; r < 4; ++r) { bias[r] = b1[pb + r]; s1[r] = 0.f; s2[r] = 0.f; }
    #pragma unroll
    for (int nf = 0; nf < 4; ++nf) {
      const int n = n0 + wn * 64 + nf * 16 + m;
      #pragma unroll
      for (int r = 0; r < 4; ++r) {
        float y = acc[of][nf][r] + bias[r];
        s1[r] += y; s2[r] += y * y;
        y1[((size_t)bz * C2_ + pb + r) * N_ + n] = y;
      }
    }
    #pragma unroll
    for (int mk = 1; mk < 16; mk <<= 1)
      #pragma unroll
      for (int r = 0; r < 4; ++r) {
        s1[r] += __shfl_xor(s1[r], mk);
        s2[r] += __shfl_xor(s2[r], mk);
      }
    if (m == 0) {
      #pragma unroll
      for (int r = 0; r < 4; ++r) {
        atomicAdd(&stats[pb + r], s1[r]);
        atomicAdd(&stats[C2_ + pb + r], s2[r]);
      }
    }
  }
}

// ---------------------------------------------------------------------------
__global__ void bn_coef_kernel(const float* __restrict__ g, const float* __restrict__ be,
                               const float* __restrict__ stats, float* __restrict__ coef,
                               int C)
{
  int o = threadIdx.x;
  if (o < C) {
    const float invM = 1.0f / 65536.0f;   // B*N
    float mean = stats[o] * invM;
    float var  = stats[C + o] * invM - mean * mean;
    float a = g[o] / sqrtf(var + BN_EPS);
    float c = be[o] - mean * a;
    coef[o] = a;
    coef[C + o] = c;
  }
}

__global__ void zero_kernel(float* __restrict__ p, int n)
{
  int i = blockIdx.x * blockDim.x + threadIdx.x;
  if (i < n) p[i] = 0.0f;
}

// ---------------------------------------------------------------------------
__global__ __launch_bounds__(256) void final_kernel(
    const float* __restrict__ y1, const float* __restrict__ cf, float* __restrict__ out)
{
  const size_t total4 = (size_t)B_ * C2_ * N_ / 4;
  const size_t stride = (size_t)gridDim.x * blockDim.x;
  for (size_t f = (size_t)blockIdx.x * blockDim.x + threadIdx.x; f < total4; f += stride) {
    size_t base = f * 4;
    int p = (int)((base >> 13) & (C2_ - 1));
    float a = cf[p], c = cf[C2_ + p];
    float4 v = *(const float4*)(y1 + base);
    float4 r;
    r.x = fmaxf(0.0f, fmaf(v.x, a, c));
    r.y = fmaxf(0.0f, fmaf(v.y, a, c));
    r.z = fmaxf(0.0f, fmaf(v.z, a, c));
    r.w = fmaxf(0.0f, fmaf(v.w, a, c));
    *(float4*)(out + base) = r;
  }
}

// ---------------------------------------------------------------------------
extern "C" void kernel_launch(void* const* d_in, const int* in_sizes, int n_in,
                              void* d_out, int out_size, void* d_ws, size_t ws_size,
                              hipStream_t stream)
{
  const float* xyz_sa     = (const float*)d_in[0];
  const float* xyz_now    = (const float*)d_in[1];
  const float* points_sa  = (const float*)d_in[2];
  const float* points_now = (const float*)d_in[3];
  const float* W0  = (const float*)d_in[4];
  const float* b0  = (const float*)d_in[5];
  const float* g0  = (const float*)d_in[6];
  const float* be0 = (const float*)d_in[7];
  const float* W1  = (const float*)d_in[8];
  const float* b1  = (const float*)d_in[9];
  const float* g1  = (const float*)d_in[10];
  const float* be1 = (const float*)d_in[11];

  const size_t MB = 1048576ull;
  char* base = (char*)d_ws;
  u16*   interpT = (u16*)(base + 0);          // [B][N][256] bf16  32MB
  u16*   psaT    = (u16*)(base + 32 * MB);    // [B][N][128] bf16  16MB
  float* pnT     = (float*)(base + 48 * MB);  // [B][S][256] f32   16MB
  u16*   y0b     = (u16*)(base + 64 * MB);    // [B][N][256] bf16  32MB
  u16*   W0b     = (u16*)(base + 96 * MB);    // 98304 bf16
  u16*   W1b     = (u16*)(base + 96 * MB + 512 * 1024); // 32768 bf16
  float* stats   = (float*)(base + 97 * MB);  // 768 f
  float* coef    = stats + 768;               // 768 f
  float* y1      = (float*)(base + 32 * MB);  // [B][C2][N] f32 32MB (aliases psaT+pnT)
  float* out     = (float*)d_out;

  hipLaunchKernelGGL(zero_kernel, dim3(1), dim3(768), 0, stream, stats, 768);
  hipLaunchKernelGGL(cvt_bf16_kernel, dim3((C1_ * C0_ + 255) / 256), dim3(256), 0, stream,
                     W0, W0b, C1_ * C0_);
  hipLaunchKernelGGL(cvt_bf16_kernel, dim3((C2_ * C1_ + 255) / 256), dim3(256), 0, stream,
                     W1, W1b, C2_ * C1_);
  hipLaunchKernelGGL(transpose_kernel, dim3(S_ / 32, D2_ / 32, B_), dim3(256), 0, stream,
                     points_now, pnT);
  hipLaunchKernelGGL(psaT_kernel, dim3(N_ / 32, D1_ / 32, B_), dim3(256), 0, stream,
                     points_sa, psaT);
  hipLaunchKernelGGL(knn_interp_kernel, dim3(N_ / 128, B_), dim3(256), 0, stream,
                     xyz_sa, xyz_now, pnT, interpT);
  hipLaunchKernelGGL(gemm1_mfma_kernel, dim3(N_ / 128, 2, B_), dim3(256), 0, stream,
                     psaT, interpT, W0b, b0, y0b, stats);
  hipLaunchKernelGGL(bn_coef_kernel, dim3(1), dim3(256), 0, stream,
                     g0, be0, stats, coef, C1_);
  hipLaunchKernelGGL(gemm2_mfma_kernel, dim3(N_ / 128, 1, B_), dim3(256), 0, stream,
                     y0b, coef, W1b, b1, y1, stats + 512);
  hipLaunchKernelGGL(bn_coef_kernel, dim3(1), dim3(128), 0, stream,
                     g1, be1, stats + 512, coef + 512, C2_);
  hipLaunchKernelGGL(final_kernel, dim3(2048), dim3(256), 0, stream,
                     y1, coef + 512, out);
}

// Round 5
// 400.076 us; speedup vs baseline: 1.7614x; 1.0182x over previous
//
#include <hip/hip_runtime.h>

#define B_ 8
#define N_ 8192
#define S_ 2048
#define D1_ 128
#define D2_ 256
#define C0_ 384
#define C1_ 256
#define C2_ 128
#define BN_EPS 1e-5f

typedef unsigned long long ull;
typedef unsigned short u16;
typedef __bf16 bf16x8 __attribute__((ext_vector_type(8)));
typedef float f32x4 __attribute__((ext_vector_type(4)));
typedef short short8_ __attribute__((ext_vector_type(8)));

__device__ __forceinline__ u16 f2bf(float x) {
  unsigned int u = __float_as_uint(x);
  unsigned int r = u + 0x7fffu + ((u >> 16) & 1u);
  return (u16)(r >> 16);
}
__device__ __forceinline__ float bf2f(u16 h) {
  return __uint_as_float(((unsigned int)h) << 16);
}

// branchless sorted-insert of key k into ascending top-3 (k0<=k1<=k2)
__device__ __forceinline__ void ins3(ull k, ull& k0, ull& k1, ull& k2) {
  ull t = k < k2 ? k : k2;
  ull u = k1 < t ? k1 : t;
  k2 = k1 < t ? t : k1;
  k1 = k0 < u ? u : k0;
  k0 = k0 < u ? k0 : u;
}

// ---------------------------------------------------------------------------
__global__ void cvt_bf16_kernel(const float* __restrict__ src, u16* __restrict__ dst, int n)
{
  int i = blockIdx.x * blockDim.x + threadIdx.x;
  if (i < n) dst[i] = f2bf(src[i]);
}

// ---------------------------------------------------------------------------
// transpose points_now [B][D2][S] -> pnT [B][S][D2]  (fp32, for knn gather)
// ---------------------------------------------------------------------------
__global__ __launch_bounds__(256) void transpose_kernel(
    const float* __restrict__ in, float* __restrict__ out)
{
  __shared__ float tile[32][33];
  const int b  = blockIdx.z;
  const int s0 = blockIdx.x * 32;
  const int d0 = blockIdx.y * 32;
  const int tx = threadIdx.x & 31, ty = threadIdx.x >> 5;

  const float* inb = in + ((size_t)b * D2_ + d0) * S_ + s0;
  #pragma unroll
  for (int r = 0; r < 4; ++r) {
    int d = r * 8 + ty;
    tile[d][tx] = inb[(size_t)d * S_ + tx];
  }
  __syncthreads();
  float* outb = out + ((size_t)b * S_ + s0) * D2_ + d0;
  #pragma unroll
  for (int r = 0; r < 4; ++r) {
    int s = r * 8 + ty;
    outb[(size_t)s * D2_ + tx] = tile[tx][s];
  }
}

// ---------------------------------------------------------------------------
// transpose+convert points_sa [B][D1][N] f32 -> psaT [B][N][D1] bf16
// ---------------------------------------------------------------------------
__global__ __launch_bounds__(256) void psaT_kernel(
    const float* __restrict__ in, u16* __restrict__ out)
{
  __shared__ float tile[32][33];
  const int b  = blockIdx.z;
  const int n0 = blockIdx.x * 32;
  const int d0 = blockIdx.y * 32;
  const int tx = threadIdx.x & 31, ty = threadIdx.x >> 5;

  const float* inb = in + ((size_t)b * D1_ + d0) * N_ + n0;
  #pragma unroll
  for (int r = 0; r < 4; ++r) {
    int d = r * 8 + ty;
    tile[d][tx] = inb[(size_t)d * N_ + tx];
  }
  __syncthreads();
  u16* outb = out + ((size_t)b * N_ + n0) * D1_ + d0;
  #pragma unroll
  for (int r = 0; r < 4; ++r) {
    int n = r * 8 + ty;
    outb[(size_t)n * D1_ + tx] = f2bf(tile[tx][n]);
  }
}

// ---------------------------------------------------------------------------
// K1: 3-NN + interpolation. 128 queries/block.
// ---------------------------------------------------------------------------
__global__ __launch_bounds__(256) void knn_interp_kernel(
    const float* __restrict__ xyz_sa, const float* __restrict__ xyz_now,
    const float* __restrict__ pnT, u16* __restrict__ interpT)
{
  __shared__ float4 sp[S_];
  __shared__ int   s_idx[128][3];
  __shared__ float s_w[128][3];

  const int b  = blockIdx.y;
  const int n0 = blockIdx.x * 128;

  const float* xb = xyz_now + (size_t)b * 3 * S_;
  for (int i = threadIdx.x; i < S_; i += 256) {
    float px = xb[i], py = xb[S_ + i], pz = xb[2 * S_ + i];
    sp[i] = make_float4(px, py, pz, px * px + py * py + pz * pz);
  }
  __syncthreads();

  const int qg = threadIdx.x >> 3;   // 0..31 query group (4 queries)
  const int t  = threadIdx.x & 7;    // scanner 0..7
  const int nb = n0 + qg * 4;

  const float* xq = xyz_sa + (size_t)b * 3 * N_;
  float qx[4], qy[4], qz[4], qq[4];
  #pragma unroll
  for (int w = 0; w < 4; ++w) {
    int n = nb + w;
    qx[w] = xq[n]; qy[w] = xq[N_ + n]; qz[w] = xq[2 * N_ + n];
    qq[w] = qx[w] * qx[w] + qy[w] * qy[w] + qz[w] * qz[w];
  }

  ull K0[4], K1[4], K2[4];
  #pragma unroll
  for (int w = 0; w < 4; ++w) { K0[w] = ~0ull; K1[w] = ~0ull; K2[w] = ~0ull; }

  #pragma unroll 2
  for (int it = 0; it < S_ / 8; ++it) {
    int s = (it << 3) | t;
    float4 p = sp[s];
    #pragma unroll
    for (int w = 0; w < 4; ++w) {
      float dot = qx[w] * p.x + qy[w] * p.y + qz[w] * p.z;
      float d = qq[w] - 2.0f * dot + p.w;
      unsigned int bits = __float_as_uint(d);
      unsigned int u = bits ^ (0x80000000u | (unsigned int)((int)bits >> 31));
      ull k = ((ull)u << 32) | (unsigned int)s;
      ins3(k, K0[w], K1[w], K2[w]);
    }
  }

  #pragma unroll
  for (int m = 1; m <= 4; m <<= 1) {
    #pragma unroll
    for (int w = 0; w < 4; ++w) {
      ull o0 = __shfl_xor(K0[w], m), o1 = __shfl_xor(K1[w], m), o2 = __shfl_xor(K2[w], m);
      ins3(o0, K0[w], K1[w], K2[w]);
      ins3(o1, K0[w], K1[w], K2[w]);
      ins3(o2, K0[w], K1[w], K2[w]);
    }
  }

  if (t == 0) {
    #pragma unroll
    for (int w = 0; w < 4; ++w) {
      unsigned int u0 = (unsigned int)(K0[w] >> 32);
      unsigned int u1 = (unsigned int)(K1[w] >> 32);
      unsigned int u2 = (unsigned int)(K2[w] >> 32);
      float d0 = __uint_as_float(u0 ^ (0x80000000u | ~(unsigned int)((int)u0 >> 31)));
      float d1 = __uint_as_float(u1 ^ (0x80000000u | ~(unsigned int)((int)u1 >> 31)));
      float d2 = __uint_as_float(u2 ^ (0x80000000u | ~(unsigned int)((int)u2 >> 31)));
      float r0 = 1.0f / (d0 + 1e-8f);
      float r1 = 1.0f / (d1 + 1e-8f);
      float r2 = 1.0f / (d2 + 1e-8f);
      float rs = 1.0f / (r0 + r1 + r2);
      int qi = qg * 4 + w;
      s_idx[qi][0] = (int)(K0[w] & 0xFFFFFFFFu);
      s_idx[qi][1] = (int)(K1[w] & 0xFFFFFFFFu);
      s_idx[qi][2] = (int)(K2[w] & 0xFFFFFFFFu);
      s_w[qi][0] = r0 * rs; s_w[qi][1] = r1 * rs; s_w[qi][2] = r2 * rs;
    }
  }
  __syncthreads();

  const int wave = threadIdx.x >> 6;
  const int lane = threadIdx.x & 63;
  const float* pb = pnT + (size_t)b * S_ * D2_;
  u16* ob = interpT + ((size_t)b * N_ + n0) * D2_;
  #pragma unroll 2
  for (int i = 0; i < 32; ++i) {
    const int qi = wave * 32 + i;
    const int j0 = s_idx[qi][0], j1 = s_idx[qi][1], j2 = s_idx[qi][2];
    const float w0 = s_w[qi][0], w1 = s_w[qi][1], w2 = s_w[qi][2];
    float4 f0 = *(const float4*)(pb + (size_t)j0 * D2_ + lane * 4);
    float4 f1 = *(const float4*)(pb + (size_t)j1 * D2_ + lane * 4);
    float4 f2 = *(const float4*)(pb + (size_t)j2 * D2_ + lane * 4);
    float rx = w0 * f0.x + w1 * f1.x + w2 * f2.x;
    float ry = w0 * f0.y + w1 * f1.y + w2 * f2.y;
    float rz = w0 * f0.z + w1 * f1.z + w2 * f2.z;
    float rw = w0 * f0.w + w1 * f1.w + w2 * f2.w;
    unsigned int lo = (unsigned int)f2bf(rx) | ((unsigned int)f2bf(ry) << 16);
    unsigned int hi = (unsigned int)f2bf(rz) | ((unsigned int)f2bf(rw) << 16);
    *(uint2*)(ob + (size_t)qi * D2_ + lane * 4) = make_uint2(lo, hi);
  }
}

// ---------------------------------------------------------------------------
// GEMM1 (MFMA bf16, double-buffered reg-prefetch pipeline):
// y0b[b,n,o] = W0[o,:] . x[b,:,n] + b0[o]; + per-channel stats.
// ---------------------------------------------------------------------------
__global__ __launch_bounds__(256, 4) void gemm1_mfma_kernel(
    const u16* __restrict__ psaT, const u16* __restrict__ interpT,
    const u16* __restrict__ W0b, const float* __restrict__ b0,
    u16* __restrict__ y0b, float* __restrict__ stats)
{
  __shared__ u16 As[2][128][40];
  __shared__ u16 Bs[2][128][40];

  const int bz = blockIdx.z;
  const int n0 = blockIdx.x * 128;
  const int o0 = blockIdx.y * 128;
  const int tid = threadIdx.x;
  const int wid = tid >> 6, lane = tid & 63;
  const int wo = wid & 1, wn = wid >> 1;
  const int m = lane & 15, g = lane >> 4;
  const int r0 = tid >> 2, cb = (tid & 3) << 3;  // staging row (h=0), k-chunk

  f32x4 acc[4][4];
  #pragma unroll
  for (int i = 0; i < 4; ++i)
    #pragma unroll
    for (int j = 0; j < 4; ++j) acc[i][j] = (f32x4){0.f, 0.f, 0.f, 0.f};

  uint4 ra[2], rb[2];

  auto gload = [&](int kt) {
    #pragma unroll
    for (int h = 0; h < 2; ++h) {
      const int row = r0 + h * 64;
      ra[h] = *(const uint4*)(W0b + (size_t)(o0 + row) * C0_ + kt + cb);
      const u16* bsrc = (kt < D1_)
          ? psaT    + (size_t)(bz * N_ + n0 + row) * D1_ + kt + cb
          : interpT + (size_t)(bz * N_ + n0 + row) * D2_ + (kt - D1_) + cb;
      rb[h] = *(const uint4*)bsrc;
    }
  };
  auto sstore = [&](int buf) {
    #pragma unroll
    for (int h = 0; h < 2; ++h) {
      const int row = r0 + h * 64;
      *(uint4*)&As[buf][row][cb] = ra[h];
      *(uint4*)&Bs[buf][row][cb] = rb[h];
    }
  };

  gload(0);
  sstore(0);
  __syncthreads();

  for (int kt = 0; kt < 12; ++kt) {
    const int cur = kt & 1;
    if (kt < 11) gload((kt + 1) << 5);   // issue early: overlaps MFMA below

    bf16x8 af[4], bfv[4];
    #pragma unroll
    for (int f = 0; f < 4; ++f)
      af[f] = __builtin_bit_cast(bf16x8, *(const short8_*)&As[cur][wo * 64 + f * 16 + m][g * 8]);
    #pragma unroll
    for (int f = 0; f < 4; ++f)
      bfv[f] = __builtin_bit_cast(bf16x8, *(const short8_*)&Bs[cur][wn * 64 + f * 16 + m][g * 8]);
    #pragma unroll
    for (int i = 0; i < 4; ++i)
      #pragma unroll
      for (int j = 0; j < 4; ++j)
        acc[i][j] = __builtin_amdgcn_mfma_f32_16x16x32_bf16(af[i], bfv[j], acc[i][j], 0, 0, 0);

    if (kt < 11) sstore(cur ^ 1);        // write late (after MFMA issues)
    __syncthreads();
  }

  // epilogue: bias, bf16 store to y0b [B][N][C1], stats
  #pragma unroll
  for (int of = 0; of < 4; ++of) {
    const int ob = o0 + wo * 64 + of * 16 + g * 4;
    float bias[4], s1[4], s2[4];
    #pragma unroll
    for (int r = 0; r < 4; ++r) { bias[r] = b0[ob + r]; s1[r] = 0.f; s2[r] = 0.f; }
    #pragma unroll
    for (int nf = 0; nf < 4; ++nf) {
      const int n = n0 + wn * 64 + nf * 16 + m;
      float y[4];
      #pragma unroll
      for (int r = 0; r < 4; ++r) {
        y[r] = acc[of][nf][r] + bias[r];
        s1[r] += y[r]; s2[r] += y[r] * y[r];
      }
      unsigned int lo = (unsigned int)f2bf(y[0]) | ((unsigned int)f2bf(y[1]) << 16);
      unsigned int hi = (unsigned int)f2bf(y[2]) | ((unsigned int)f2bf(y[3]) << 16);
      *(uint2*)(y0b + (size_t)(bz * N_ + n) * C1_ + ob) = make_uint2(lo, hi);
    }
    #pragma unroll
    for (int mk = 1; mk < 16; mk <<= 1)
      #pragma unroll
      for (int r = 0; r < 4; ++r) {
        s1[r] += __shfl_xor(s1[r], mk);
        s2[r] += __shfl_xor(s2[r], mk);
      }
    if (m == 0) {
      #pragma unroll
      for (int r = 0; r < 4; ++r) {
        atomicAdd(&stats[ob + r], s1[r]);
        atomicAdd(&stats[C1_ + ob + r], s2[r]);
      }
    }
  }
}

// ---------------------------------------------------------------------------
// GEMM2 (MFMA bf16, same pipeline): y1b[b,p,n] = W1 . relu(bn0(y0)) + b1 (bf16 out)
// BN0+ReLU folded into the staging store; coef cached in LDS.
// ---------------------------------------------------------------------------
__global__ __launch_bounds__(256, 4) void gemm2_mfma_kernel(
    const u16* __restrict__ y0b, const float* __restrict__ coef,
    const u16* __restrict__ W1b, const float* __restrict__ b1,
    u16* __restrict__ y1b, float* __restrict__ stats)
{
  __shared__ u16 As[2][128][40];
  __shared__ u16 Bs[2][128][40];
  __shared__ float cfa[C1_], cfc[C1_];

  const int bz = blockIdx.z;
  const int n0 = blockIdx.x * 128;
  const int tid = threadIdx.x;
  const int wid = tid >> 6, lane = tid & 63;
  const int wo = wid & 1, wn = wid >> 1;
  const int m = lane & 15, g = lane >> 4;
  const int r0 = tid >> 2, cb = (tid & 3) << 3;

  f32x4 acc[4][4];
  #pragma unroll
  for (int i = 0; i < 4; ++i)
    #pragma unroll
    for (int j = 0; j < 4; ++j) acc[i][j] = (f32x4){0.f, 0.f, 0.f, 0.f};

  cfa[tid] = coef[tid];
  cfc[tid] = coef[C1_ + tid];

  uint4 ra[2], rb[2];
  int kst = 0;

  auto gload = [&](int kt) {
    kst = kt;
    #pragma unroll
    for (int h = 0; h < 2; ++h) {
      const int row = r0 + h * 64;
      ra[h] = *(const uint4*)(W1b + (size_t)row * C1_ + kt + cb);
      rb[h] = *(const uint4*)(y0b + (size_t)(bz * N_ + n0 + row) * C1_ + kt + cb);
    }
  };
  auto sstore = [&](int buf) {
    const int cg = kst + cb;
    #pragma unroll
    for (int h = 0; h < 2; ++h) {
      const int row = r0 + h * 64;
      *(uint4*)&As[buf][row][cb] = ra[h];
      uint4 v = rb[h];
      float f0 = fmaxf(0.f, fmaf(bf2f((u16)(v.x & 0xffff)), cfa[cg + 0], cfc[cg + 0]));
      float f1 = fmaxf(0.f, fmaf(bf2f((u16)(v.x >> 16)),    cfa[cg + 1], cfc[cg + 1]));
      float f2 = fmaxf(0.f, fmaf(bf2f((u16)(v.y & 0xffff)), cfa[cg + 2], cfc[cg + 2]));
      float f3 = fmaxf(0.f, fmaf(bf2f((u16)(v.y >> 16)),    cfa[cg + 3], cfc[cg + 3]));
      float f4 = fmaxf(0.f, fmaf(bf2f((u16)(v.z & 0xffff)), cfa[cg + 4], cfc[cg + 4]));
      float f5 = fmaxf(0.f, fmaf(bf2f((u16)(v.z >> 16)),    cfa[cg + 5], cfc[cg + 5]));
      float f6 = fmaxf(0.f, fmaf(bf2f((u16)(v.w & 0xffff)), cfa[cg + 6], cfc[cg + 6]));
      float f7 = fmaxf(0.f, fmaf(bf2f((u16)(v.w >> 16)),    cfa[cg + 7], cfc[cg + 7]));
      uint4 o;
      o.x = (unsigned int)f2bf(f0) | ((unsigned int)f2bf(f1) << 16);
      o.y = (unsigned int)f2bf(f2) | ((unsigned int)f2bf(f3) << 16);
      o.z = (unsigned int)f2bf(f4) | ((unsigned int)f2bf(f5) << 16);
      o.w = (unsigned int)f2bf(f6) | ((unsigned int)f2bf(f7) << 16);
      *(uint4*)&Bs[buf][row][cb] = o;
    }
  };

  gload(0);
  __syncthreads();     // cfa/cfc ready
  sstore(0);
  __syncthreads();

  for (int kt = 0; kt < 8; ++kt) {
    const int cur = kt & 1;
    int knext = kst;
    if (kt < 7) { gload((kt + 1) << 5); knext = kst; }

    bf16x8 af[4], bfv[4];
    #pragma unroll
    for (int f = 0; f < 4; ++f)
      af[f] = __builtin_bit_cast(bf16x8, *(const short8_*)&As[cur][wo * 64 + f * 16 + m][g * 8]);
    #pragma unroll
    for (int f = 0; f < 4; ++f)
      bfv[f] = __builtin_bit_cast(bf16x8, *(const short8_*)&Bs[cur][wn * 64 + f * 16 + m][g * 8]);
    #pragma unroll
    for (int i = 0; i < 4; ++i)
      #pragma unroll
      for (int j = 0; j < 4; ++j)
        acc[i][j] = __builtin_amdgcn_mfma_f32_16x16x32_bf16(af[i], bfv[j], acc[i][j], 0, 0, 0);

    if (kt < 7) sstore(cur ^ 1);
    __syncthreads();
  }

  #pragma unroll
  for (int of = 0; of < 4; ++of) {
    const int pb = wo * 64 + of * 16 + g * 4;
    float bias[4], s1[4], s2[4];
    #pragma unroll
    for (int r = 0; r < 4; ++r) { bias[r] = b1[pb + r]; s1[r] = 0.f; s2[r] = 0.f; }
    #pragma unroll
    for (int nf = 0; nf < 4; ++nf) {
      const int n = n0 + wn * 64 + nf * 16 + m;
      #pragma unroll
      for (int r = 0; r < 4; ++r) {
        float y = acc[of][nf][r] + bias[r];
        s1[r] += y; s2[r] += y * y;
        y1b[((size_t)bz * C2_ + pb + r) * N_ + n] = f2bf(y);
      }
    }
    #pragma unroll
    for (int mk = 1; mk < 16; mk <<= 1)
      #pragma unroll
      for (int r = 0; r < 4; ++r) {
        s1[r] += __shfl_xor(s1[r], mk);
        s2[r] += __shfl_xor(s2[r], mk);
      }
    if (m == 0) {
      #pragma unroll
      for (int r = 0; r < 4; ++r) {
        atomicAdd(&stats[pb + r], s1[r]);
        atomicAdd(&stats[C2_ + pb + r], s2[r]);
      }
    }
  }
}

// ---------------------------------------------------------------------------
__global__ void bn_coef_kernel(const float* __restrict__ g, const float* __restrict__ be,
                               const float* __restrict__ stats, float* __restrict__ coef,
                               int C)
{
  int o = threadIdx.x;
  if (o < C) {
    const float invM = 1.0f / 65536.0f;   // B*N
    float mean = stats[o] * invM;
    float var  = stats[C + o] * invM - mean * mean;
    float a = g[o] / sqrtf(var + BN_EPS);
    float c = be[o] - mean * a;
    coef[o] = a;
    coef[C + o] = c;
  }
}

__global__ void zero_kernel(float* __restrict__ p, int n)
{
  int i = blockIdx.x * blockDim.x + threadIdx.x;
  if (i < n) p[i] = 0.0f;
}

// ---------------------------------------------------------------------------
// final: BN1 + ReLU elementwise, bf16 in -> fp32 out
// ---------------------------------------------------------------------------
__global__ __launch_bounds__(256) void final_kernel(
    const u16* __restrict__ y1b, const float* __restrict__ cf, float* __restrict__ out)
{
  const size_t total4 = (size_t)B_ * C2_ * N_ / 4;
  const size_t stride = (size_t)gridDim.x * blockDim.x;
  for (size_t f = (size_t)blockIdx.x * blockDim.x + threadIdx.x; f < total4; f += stride) {
    size_t base = f * 4;
    int p = (int)((base >> 13) & (C2_ - 1));
    float a = cf[p], c = cf[C2_ + p];
    uint2 v = *(const uint2*)(y1b + base);
    float4 r;
    r.x = fmaxf(0.0f, fmaf(bf2f((u16)(v.x & 0xffff)), a, c));
    r.y = fmaxf(0.0f, fmaf(bf2f((u16)(v.x >> 16)),    a, c));
    r.z = fmaxf(0.0f, fmaf(bf2f((u16)(v.y & 0xffff)), a, c));
    r.w = fmaxf(0.0f, fmaf(bf2f((u16)(v.y >> 16)),    a, c));
    *(float4*)(out + base) = r;
  }
}

// ---------------------------------------------------------------------------
extern "C" void kernel_launch(void* const* d_in, const int* in_sizes, int n_in,
                              void* d_out, int out_size, void* d_ws, size_t ws_size,
                              hipStream_t stream)
{
  const float* xyz_sa     = (const float*)d_in[0];
  const float* xyz_now    = (const float*)d_in[1];
  const float* points_sa  = (const float*)d_in[2];
  const float* points_now = (const float*)d_in[3];
  const float* W0  = (const float*)d_in[4];
  const float* b0  = (const float*)d_in[5];
  const float* g0  = (const float*)d_in[6];
  const float* be0 = (const float*)d_in[7];
  const float* W1  = (const float*)d_in[8];
  const float* b1  = (const float*)d_in[9];
  const float* g1  = (const float*)d_in[10];
  const float* be1 = (const float*)d_in[11];

  const size_t MB = 1048576ull;
  char* base = (char*)d_ws;
  u16*   interpT = (u16*)(base + 0);          // [B][N][256] bf16  32MB
  u16*   psaT    = (u16*)(base + 32 * MB);    // [B][N][128] bf16  16MB
  float* pnT     = (float*)(base + 48 * MB);  // [B][S][256] f32   16MB (dead after knn)
  u16*   y1b     = (u16*)(base + 48 * MB);    // [B][C2][N] bf16   16MB (overlays pnT)
  u16*   y0b     = (u16*)(base + 64 * MB);    // [B][N][256] bf16  32MB
  u16*   W0b     = (u16*)(base + 96 * MB);    // 98304 bf16
  u16*   W1b     = (u16*)(base + 96 * MB + 512 * 1024); // 32768 bf16
  float* stats   = (float*)(base + 97 * MB);  // 768 f
  float* coef    = stats + 768;               // 768 f
  float* out     = (float*)d_out;

  hipLaunchKernelGGL(zero_kernel, dim3(1), dim3(768), 0, stream, stats, 768);
  hipLaunchKernelGGL(cvt_bf16_kernel, dim3((C1_ * C0_ + 255) / 256), dim3(256), 0, stream,
                     W0, W0b, C1_ * C0_);
  hipLaunchKernelGGL(cvt_bf16_kernel, dim3((C2_ * C1_ + 255) / 256), dim3(256), 0, stream,
                     W1, W1b, C2_ * C1_);
  hipLaunchKernelGGL(transpose_kernel, dim3(S_ / 32, D2_ / 32, B_), dim3(256), 0, stream,
                     points_now, pnT);
  hipLaunchKernelGGL(psaT_kernel, dim3(N_ / 32, D1_ / 32, B_), dim3(256), 0, stream,
                     points_sa, psaT);
  hipLaunchKernelGGL(knn_interp_kernel, dim3(N_ / 128, B_), dim3(256), 0, stream,
                     xyz_sa, xyz_now, pnT, interpT);
  hipLaunchKernelGGL(gemm1_mfma_kernel, dim3(N_ / 128, 2, B_), dim3(256), 0, stream,
                     psaT, interpT, W0b, b0, y0b, stats);
  hipLaunchKernelGGL(bn_coef_kernel, dim3(1), dim3(256), 0, stream,
                     g0, be0, stats, coef, C1_);
  hipLaunchKernelGGL(gemm2_mfma_kernel, dim3(N_ / 128, 1, B_), dim3(256), 0, stream,
                     y0b, coef, W1b, b1, y1b, stats + 512);
  hipLaunchKernelGGL(bn_coef_kernel, dim3(1), dim3(128), 0, stream,
                     g1, be1, stats + 512, coef + 512, C2_);
  hipLaunchKernelGGL(final_kernel, dim3(2048), dim3(256), 0, stream,
                     y1b, coef + 512, out);
}